// Round 2
// baseline (572.367 us; speedup 1.0000x reference)
//
#include <hip/hip_runtime.h>
#include <hip/hip_bf16.h>
#include <math.h>

#define B_    2
#define L_    4096
#define DM    1024
#define DI    2048
#define DS    128
#define NH    32
#define HD    64
#define CHUNK 64
#define NC    (L_/CHUNK)          // 64
#define CD    (DI + 2*DS)         // 2304
#define ROWS  (B_*L_)             // 8192
#define NOUT  (2*DI + 2*DS + NH)  // 4384
#define NPAD  4480                // 35*128

typedef __attribute__((ext_vector_type(4))) float f32x4;
typedef __attribute__((ext_vector_type(8))) __bf16 bf16x8;
typedef __attribute__((ext_vector_type(4))) short s16x4;

// ---------------- conversion kernels ----------------
__global__ __launch_bounds__(256) void k_f32_to_bf16(const float* __restrict__ s, __bf16* __restrict__ d, int n) {
    int i = blockIdx.x * 256 + threadIdx.x;
    if (i < n) d[i] = (__bf16)s[i];
}

__global__ __launch_bounds__(256) void k_convert_pad(const float* __restrict__ s, __bf16* __restrict__ d, int nsrc, int ndst) {
    int i = blockIdx.x * 256 + threadIdx.x;
    if (i < ndst) d[i] = (i < nsrc) ? (__bf16)s[i] : (__bf16)0.f;
}

// ---------------- GEMM core (NT, bf16 MFMA, 128x128 tile, BK=64) ----------------
__device__ __forceinline__ void gemm_core(const __bf16* __restrict__ Ag, const __bf16* __restrict__ Bg,
                                          int K, int m0, int n0,
                                          __bf16* As, __bf16* Bs, f32x4 acc[4][4]) {
    const int tid  = threadIdx.x;
    const int wave = tid >> 6;
    const int lane = tid & 63;
    const int wm   = wave >> 1, wn = wave & 1;
    const int lrow = lane & 15;
    const int lko  = (lane >> 4) * 8;

    for (int kt = 0; kt < K; kt += 64) {
        // stage 128x64 bf16 A and B tiles via global_load_lds (16B/lane, wave-linear dest)
#pragma unroll
        for (int i = 0; i < 4; i++) {
            int e   = (wave * 4 + i) * 512 + lane * 8;  // element index in tile
            int row = e >> 6, col = e & 63;
            const __bf16* sa = Ag + (size_t)(m0 + row) * K + kt + col;
            const __bf16* sb = Bg + (size_t)(n0 + row) * K + kt + col;
            __builtin_amdgcn_global_load_lds((const __attribute__((address_space(1))) void*)sa,
                                             (__attribute__((address_space(3))) void*)(As + (wave * 4 + i) * 512),
                                             16, 0, 0);
            __builtin_amdgcn_global_load_lds((const __attribute__((address_space(1))) void*)sb,
                                             (__attribute__((address_space(3))) void*)(Bs + (wave * 4 + i) * 512),
                                             16, 0, 0);
        }
        __syncthreads();
#pragma unroll
        for (int ks = 0; ks < 2; ks++) {
            bf16x8 av[4], bv[4];
#pragma unroll
            for (int mi = 0; mi < 4; mi++)
                av[mi] = *(const bf16x8*)(As + (wm * 64 + mi * 16 + lrow) * 64 + ks * 32 + lko);
#pragma unroll
            for (int ni = 0; ni < 4; ni++)
                bv[ni] = *(const bf16x8*)(Bs + (wn * 64 + ni * 16 + lrow) * 64 + ks * 32 + lko);
#pragma unroll
            for (int mi = 0; mi < 4; mi++)
#pragma unroll
                for (int ni = 0; ni < 4; ni++)
                    acc[mi][ni] = __builtin_amdgcn_mfma_f32_16x16x32_bf16(av[mi], bv[ni], acc[mi][ni], 0, 0, 0);
        }
        __syncthreads();
    }
}

// GEMM1: zxbcdt = u @ W_in^T, fused split + softplus epilogue
__global__ __launch_bounds__(256) void k_gemm1(const __bf16* __restrict__ ubf, const __bf16* __restrict__ wibf,
                                               __bf16* __restrict__ zbuf, __bf16* __restrict__ xbcraw,
                                               float* __restrict__ dtbuf, const float* __restrict__ dt_bias) {
    __shared__ __align__(16) __bf16 As[128 * 64];
    __shared__ __align__(16) __bf16 Bs[128 * 64];
    f32x4 acc[4][4];
    f32x4 z4 = {0.f, 0.f, 0.f, 0.f};
#pragma unroll
    for (int i = 0; i < 4; i++)
#pragma unroll
        for (int j = 0; j < 4; j++) acc[i][j] = z4;

    int m0 = blockIdx.y * 128, n0 = blockIdx.x * 128;
    gemm_core(ubf, wibf, DM, m0, n0, As, Bs, acc);

    const int lane = threadIdx.x & 63, wave = threadIdx.x >> 6;
    const int wm = wave >> 1, wn = wave & 1;
    const int gm_base = m0 + wm * 64 + (lane >> 4) * 4;
    const int gn_base = n0 + wn * 64 + (lane & 15);
#pragma unroll
    for (int mi = 0; mi < 4; mi++)
#pragma unroll
        for (int ni = 0; ni < 4; ni++) {
            int gn = gn_base + ni * 16;
            if (gn >= NOUT) continue;
#pragma unroll
            for (int r = 0; r < 4; r++) {
                int gm = gm_base + mi * 16 + r;
                float v = acc[mi][ni][r];
                if (gn < DI) {
                    zbuf[(size_t)gm * DI + gn] = (__bf16)v;
                } else if (gn < DI + CD) {
                    xbcraw[(size_t)gm * CD + (gn - DI)] = (__bf16)v;
                } else {
                    int hh = gn - (DI + CD);
                    float x = v + dt_bias[hh];
                    float sp = (x > 20.f) ? x : log1pf(__expf(x));
                    dtbuf[(size_t)gm * NH + hh] = sp;
                }
            }
        }
}

// GEMM2: out = ynorm @ W_out^T
__global__ __launch_bounds__(256) void k_gemm2(const __bf16* __restrict__ ybf, const __bf16* __restrict__ wobf,
                                               float* __restrict__ out) {
    __shared__ __align__(16) __bf16 As[128 * 64];
    __shared__ __align__(16) __bf16 Bs[128 * 64];
    f32x4 acc[4][4];
    f32x4 z4 = {0.f, 0.f, 0.f, 0.f};
#pragma unroll
    for (int i = 0; i < 4; i++)
#pragma unroll
        for (int j = 0; j < 4; j++) acc[i][j] = z4;

    int m0 = blockIdx.y * 128, n0 = blockIdx.x * 128;
    gemm_core(ybf, wobf, DI, m0, n0, As, Bs, acc);

    const int lane = threadIdx.x & 63, wave = threadIdx.x >> 6;
    const int wm = wave >> 1, wn = wave & 1;
    const int gm_base = m0 + wm * 64 + (lane >> 4) * 4;
    const int gn_base = n0 + wn * 64 + (lane & 15);
#pragma unroll
    for (int mi = 0; mi < 4; mi++)
#pragma unroll
        for (int ni = 0; ni < 4; ni++) {
            int gn = gn_base + ni * 16;
#pragma unroll
            for (int r = 0; r < 4; r++) {
                int gm = gm_base + mi * 16 + r;
                out[(size_t)gm * DM + gn] = acc[mi][ni][r];
            }
        }
}

// ---------------- depthwise causal conv + SiLU ----------------
__global__ __launch_bounds__(256) void k_conv(const __bf16* __restrict__ xbcraw, const float* __restrict__ conv_w,
                                              const float* __restrict__ conv_b, __bf16* __restrict__ xconv) {
    size_t idx = (size_t)blockIdx.x * 256 + threadIdx.x;
    if (idx >= (size_t)ROWS * CD) return;
    int ch = (int)(idx % CD);
    size_t rem = idx / CD;
    int l = (int)(rem % L_);
    int b = (int)(rem / L_);
    float acc = conv_b[ch];
#pragma unroll
    for (int k = 0; k < 4; k++) {
        int ll = l - 3 + k;
        if (ll >= 0) acc += conv_w[ch * 4 + k] * (float)xbcraw[((size_t)b * L_ + ll) * CD + ch];
    }
    xconv[idx] = (__bf16)(acc / (1.f + __expf(-acc)));  // silu
}

// ---------------- CBT[b][c][i][j] = sum_n C[i][n]*B[j][n] ----------------
__global__ __launch_bounds__(256) void k_cbt(const __bf16* __restrict__ xconv, float* __restrict__ cbt) {
    const int c = blockIdx.x, b = blockIdx.y;
    const int tid = threadIdx.x;
    __shared__ __bf16 Bs2[64 * 128];
    __shared__ __bf16 Cs2[64 * 128];
    const size_t rowbase = (size_t)b * L_ + c * CHUNK;
#pragma unroll
    for (int q = 0; q < 32; q++) {
        int e = q * 256 + tid;
        int i = e >> 7, n = e & 127;
        const __bf16* base = xconv + (rowbase + i) * CD + DI;
        Bs2[e] = base[n];
        Cs2[e] = base[DS + n];
    }
    __syncthreads();
    const int ty = tid >> 4, tx = tid & 15;
    const int i0 = ty * 4, j0 = tx * 4;
    float a[4][4] = {};
    for (int n = 0; n < 128; n++) {
        float cv[4], bv[4];
#pragma unroll
        for (int ii = 0; ii < 4; ii++) cv[ii] = (float)Cs2[(i0 + ii) * 128 + n];
#pragma unroll
        for (int jj = 0; jj < 4; jj++) bv[jj] = (float)Bs2[(j0 + jj) * 128 + n];
#pragma unroll
        for (int ii = 0; ii < 4; ii++)
#pragma unroll
            for (int jj = 0; jj < 4; jj++) a[ii][jj] += cv[ii] * bv[jj];
    }
    float* o = cbt + ((size_t)(b * NC + c)) * 64 * 64;
#pragma unroll
    for (int ii = 0; ii < 4; ii++)
#pragma unroll
        for (int jj = 0; jj < 4; jj++) o[(i0 + ii) * 64 + j0 + jj] = a[ii][jj];
}

// ---------------- SSD part A: Y_diag + D-skip, chunk states ----------------
__global__ __launch_bounds__(256) void k_ssd_a(const __bf16* __restrict__ xconv, const float* __restrict__ dtbuf,
                                               const float* __restrict__ cbt, const float* __restrict__ A_log,
                                               __bf16* __restrict__ ybuf, __bf16* __restrict__ states,
                                               float* __restrict__ asum, const float* __restrict__ D_param) {
    const int h = blockIdx.x, c = blockIdx.y, b = blockIdx.z;
    const int tid = threadIdx.x;
    __shared__ float xs[64][65];   // raw x chunk
    __shared__ float Ms[64][65];   // masked decay matrix (incl dt_j)
    __shared__ __bf16 Bsh[64 * 128];
    __shared__ float dts[64], cum[64], dcf[64];

    const float Ah = -__expf(A_log[h]);
    const size_t rowbase = (size_t)b * L_ + c * CHUNK;

    if (tid < 64) dts[tid] = dtbuf[(rowbase + tid) * NH + h];
#pragma unroll
    for (int q = 0; q < 16; q++) {
        int e = q * 256 + tid;
        int i = e >> 6, p = e & 63;
        xs[i][p] = (float)xconv[(rowbase + i) * CD + h * HD + p];
    }
#pragma unroll
    for (int q = 0; q < 32; q++) {
        int e = q * 256 + tid;
        int i = e >> 7, n = e & 127;
        Bsh[e] = xconv[(rowbase + i) * CD + DI + n];
    }
    __syncthreads();
    if (tid == 0) {
        float run = 0.f;
        for (int i = 0; i < 64; i++) { run += Ah * dts[i]; cum[i] = run; }
        asum[(b * NC + c) * NH + h] = run;
    }
    __syncthreads();
    if (tid < 64) dcf[tid] = __expf(cum[63] - cum[tid]) * dts[tid];
    const float* cbt_bc = cbt + ((size_t)(b * NC + c)) * 64 * 64;
#pragma unroll
    for (int q = 0; q < 16; q++) {
        int e = q * 256 + tid;
        int i = e >> 6, j = e & 63;
        float m = 0.f;
        if (j <= i) m = cbt_bc[e] * __expf(cum[i] - cum[j]) * dts[j];
        Ms[i][j] = m;
    }
    __syncthreads();

    // Y_diag = M @ x  (then + x*D)
    {
        const int ty = tid >> 4, tx = tid & 15;
        const int i0 = ty * 4, p0 = tx * 4;
        float accd[4][4] = {};
        for (int j = 0; j < 64; j++) {
            float mv[4], xv[4];
#pragma unroll
            for (int ii = 0; ii < 4; ii++) mv[ii] = Ms[i0 + ii][j];
#pragma unroll
            for (int pp = 0; pp < 4; pp++) xv[pp] = xs[j][p0 + pp];
#pragma unroll
            for (int ii = 0; ii < 4; ii++)
#pragma unroll
                for (int pp = 0; pp < 4; pp++) accd[ii][pp] += mv[ii] * xv[pp];
        }
        const float Dh = D_param[h];
#pragma unroll
        for (int ii = 0; ii < 4; ii++)
#pragma unroll
            for (int pp = 0; pp < 4; pp++) {
                int i = i0 + ii, p = p0 + pp;
                ybuf[(rowbase + i) * DI + h * HD + p] = (__bf16)(accd[ii][pp] + xs[i][p] * Dh);
            }
    }
    // chunk state: state[p][n] = sum_i dcf[i]*x[i][p]*B[i][n]
    {
        const int tp = tid >> 5, tn = tid & 31;
        const int p0 = tp * 8, n0 = tn * 4;
        float st[8][4] = {};
        for (int i = 0; i < 64; i++) {
            float d = dcf[i];
            float xv[8], bv[4];
#pragma unroll
            for (int pp = 0; pp < 8; pp++) xv[pp] = xs[i][p0 + pp] * d;
#pragma unroll
            for (int nn = 0; nn < 4; nn++) bv[nn] = (float)Bsh[i * 128 + n0 + nn];
#pragma unroll
            for (int pp = 0; pp < 8; pp++)
#pragma unroll
                for (int nn = 0; nn < 4; nn++) st[pp][nn] += xv[pp] * bv[nn];
        }
        __bf16* sp = states + (((size_t)(b * NC + c) * NH + h) * 64 * 128);
#pragma unroll
        for (int pp = 0; pp < 8; pp++)
#pragma unroll
            for (int nn = 0; nn < 4; nn++) sp[(p0 + pp) * 128 + n0 + nn] = (__bf16)st[pp][nn];
    }
}

// ---------------- inter-chunk scan (in-place: chunk_states -> states_prev) ----------------
__global__ __launch_bounds__(256) void k_scan(__bf16* __restrict__ states, const float* __restrict__ asum) {
    const int seg = blockIdx.x, h = blockIdx.y, b = blockIdx.z;
    const int e0 = seg * 1024 + threadIdx.x * 4;
    float S[4] = {0.f, 0.f, 0.f, 0.f};
    for (int c = 0; c < NC; c++) {
        float ef = __expf(asum[(b * NC + c) * NH + h]);
        __bf16* ptr = states + (((size_t)(b * NC + c) * NH + h) * 8192) + e0;
        s16x4 raw = *(const s16x4*)ptr;
        s16x4 outv;
#pragma unroll
        for (int q = 0; q < 4; q++) {
            float t = (float)__builtin_bit_cast(__bf16, (short)raw[q]);
            outv[q] = __builtin_bit_cast(short, (__bf16)S[q]);
            S[q] = ef * S[q] + t;
        }
        *(s16x4*)ptr = outv;
    }
}

// ---------------- SSD part B: Y_off += C @ Sprev^T * exp(cumA) ----------------
__global__ __launch_bounds__(256) void k_ssd_b(const __bf16* __restrict__ xconv, const float* __restrict__ dtbuf,
                                               const __bf16* __restrict__ states, const float* __restrict__ A_log,
                                               __bf16* __restrict__ ybuf) {
    const int h = blockIdx.x, c = blockIdx.y, b = blockIdx.z;
    const int tid = threadIdx.x;
    __shared__ float Sp[64][129];
    __shared__ __bf16 Csh[64 * 128];
    __shared__ float dts[64], cum[64];

    const float Ah = -__expf(A_log[h]);
    const size_t rowbase = (size_t)b * L_ + c * CHUNK;
    if (tid < 64) dts[tid] = dtbuf[(rowbase + tid) * NH + h];
    const __bf16* sp = states + (((size_t)(b * NC + c) * NH + h) * 8192);
#pragma unroll
    for (int q = 0; q < 32; q++) {
        int e = q * 256 + tid;
        int p = e >> 7, n = e & 127;
        Sp[p][n] = (float)sp[e];
        int i = p;  // reuse mapping for C load
        Csh[e] = xconv[(rowbase + i) * CD + DI + DS + n];
    }
    __syncthreads();
    if (tid == 0) {
        float run = 0.f;
        for (int i = 0; i < 64; i++) { run += Ah * dts[i]; cum[i] = run; }
    }
    __syncthreads();

    const int ty = tid >> 4, tx = tid & 15;
    const int i0 = ty * 4, p0 = tx * 4;
    float accd[4][4] = {};
    for (int n = 0; n < 128; n++) {
        float cv[4], sv[4];
#pragma unroll
        for (int ii = 0; ii < 4; ii++) cv[ii] = (float)Csh[(i0 + ii) * 128 + n];
#pragma unroll
        for (int pp = 0; pp < 4; pp++) sv[pp] = Sp[p0 + pp][n];
#pragma unroll
        for (int ii = 0; ii < 4; ii++)
#pragma unroll
            for (int pp = 0; pp < 4; pp++) accd[ii][pp] += cv[ii] * sv[pp];
    }
#pragma unroll
    for (int ii = 0; ii < 4; ii++) {
        int i = i0 + ii;
        float e = __expf(cum[i]);
#pragma unroll
        for (int pp = 0; pp < 4; pp++) {
            size_t idx = (rowbase + i) * DI + h * HD + p0 + pp;
            float y0 = (float)ybuf[idx];
            ybuf[idx] = (__bf16)(y0 + e * accd[ii][pp]);
        }
    }
}

// ---------------- gate (silu(z)) + RMSNorm -> bf16 ----------------
__global__ __launch_bounds__(256) void k_gate_norm(const __bf16* __restrict__ ybuf, const __bf16* __restrict__ zbuf,
                                                   const float* __restrict__ norm_w, __bf16* __restrict__ ybf) {
    const int r = blockIdx.x;
    const int tid = threadIdx.x;
    float v[8];
    float ss = 0.f;
#pragma unroll
    for (int q = 0; q < 8; q++) {
        int col = q * 256 + tid;
        float y = (float)ybuf[(size_t)r * DI + col];
        float z = (float)zbuf[(size_t)r * DI + col];
        float g = z / (1.f + __expf(-z));
        float val = y * g;
        v[q] = val;
        ss += val * val;
    }
#pragma unroll
    for (int o = 32; o > 0; o >>= 1) ss += __shfl_down(ss, o);
    __shared__ float wsum[4];
    __shared__ float rmss;
    if ((tid & 63) == 0) wsum[tid >> 6] = ss;
    __syncthreads();
    if (tid == 0) {
        float t = wsum[0] + wsum[1] + wsum[2] + wsum[3];
        rmss = rsqrtf(t / (float)DI + 1e-5f);
    }
    __syncthreads();
    float rm = rmss;
#pragma unroll
    for (int q = 0; q < 8; q++) {
        int col = q * 256 + tid;
        ybf[(size_t)r * DI + col] = (__bf16)(v[q] * rm * norm_w[col]);
    }
}

// ---------------- launcher ----------------
extern "C" void kernel_launch(void* const* d_in, const int* in_sizes, int n_in,
                              void* d_out, int out_size, void* d_ws, size_t ws_size,
                              hipStream_t stream) {
    const float* u       = (const float*)d_in[0];
    const float* W_in    = (const float*)d_in[1];
    const float* conv_w  = (const float*)d_in[2];
    const float* conv_b  = (const float*)d_in[3];
    const float* dt_bias = (const float*)d_in[4];
    const float* A_log   = (const float*)d_in[5];
    const float* D_param = (const float*)d_in[6];
    const float* norm_w  = (const float*)d_in[7];
    const float* W_out   = (const float*)d_in[8];
    float* out = (float*)d_out;

    // ---- static workspace plan (145.8 MB total) ----
    // wobf   [0,               4,194,304)
    // zbuf   [4,194,304,       37,748,736)
    // dtbuf  [37,748,736,      38,797,312)
    // asum   [38,797,312,      38,813,696)
    // xconv  [38,813,696,      76,562,432)   (later reused as ybf)
    // cbt    [76,562,432,      78,659,584)
    // BIG    [78,659,584,      145,768,448)  phase1: ubf|wibf|xbcraw ; phase2: states
    constexpr size_t OFF_WOBF  = 0;
    constexpr size_t OFF_ZBUF  = 4194304;
    constexpr size_t OFF_DT    = 37748736;
    constexpr size_t OFF_ASUM  = 38797312;
    constexpr size_t OFF_XCONV = 38813696;
    constexpr size_t OFF_CBT   = 76562432;
    constexpr size_t OFF_BIG   = 78659584;
    constexpr size_t NEED      = 145768448;
    if (ws_size < NEED) return;  // diagnostic: bench will show absmax==5.3125 (zero output)

    char* ws = (char*)d_ws;
    __bf16* wobf   = (__bf16*)(ws + OFF_WOBF);
    __bf16* zbuf   = (__bf16*)(ws + OFF_ZBUF);
    float*  dtbuf  = (float*) (ws + OFF_DT);
    float*  asum   = (float*) (ws + OFF_ASUM);
    __bf16* xconv  = (__bf16*)(ws + OFF_XCONV);
    float*  cbt    = (float*) (ws + OFF_CBT);
    __bf16* ubf    = (__bf16*)(ws + OFF_BIG);                       // 16,777,216 B
    __bf16* wibf   = (__bf16*)(ws + OFF_BIG + 16777216);            //  9,175,040 B
    __bf16* xbcraw = (__bf16*)(ws + OFF_BIG + 25952256);            // 37,748,736 B
    __bf16* states = (__bf16*)(ws + OFF_BIG);                       // 67,108,864 B (after conv)
    __bf16* ybf    = (__bf16*)(ws + OFF_XCONV);                     // 33,554,432 B (after ssd_b)
    __bf16* ybuf   = (__bf16*)d_out;                                // 33,554,432 B scratch (bf16), overwritten by gemm2

    k_f32_to_bf16<<<(ROWS * DM + 255) / 256, 256, 0, stream>>>(u, ubf, ROWS * DM);
    k_convert_pad<<<(NPAD * DM + 255) / 256, 256, 0, stream>>>(W_in, wibf, NOUT * DM, NPAD * DM);
    k_f32_to_bf16<<<(DM * DI + 255) / 256, 256, 0, stream>>>(W_out, wobf, DM * DI);

    k_gemm1<<<dim3(NPAD / 128, ROWS / 128), 256, 0, stream>>>(ubf, wibf, zbuf, xbcraw, dtbuf, dt_bias);
    k_conv<<<(int)(((size_t)ROWS * CD + 255) / 256), 256, 0, stream>>>(xbcraw, conv_w, conv_b, xconv);
    k_cbt<<<dim3(NC, B_), 256, 0, stream>>>(xconv, cbt);
    k_ssd_a<<<dim3(NH, NC, B_), 256, 0, stream>>>(xconv, dtbuf, cbt, A_log, ybuf, states, asum, D_param);
    k_scan<<<dim3(8, NH, B_), 256, 0, stream>>>(states, asum);
    k_ssd_b<<<dim3(NH, NC, B_), 256, 0, stream>>>(xconv, dtbuf, states, A_log, ybuf);
    k_gate_norm<<<ROWS, 256, 0, stream>>>(ybuf, zbuf, norm_w, ybf);
    k_gemm2<<<dim3(DM / 128, ROWS / 128), 256, 0, stream>>>(ybf, wobf, out);
}

// Round 3
// 442.969 us; speedup vs baseline: 1.2921x; 1.2921x over previous
//
#include <hip/hip_runtime.h>
#include <hip/hip_bf16.h>
#include <math.h>

#define B_    2
#define L_    4096
#define DM    1024
#define DI    2048
#define DS    128
#define NH    32
#define HD    64
#define CHUNK 64
#define NC    (L_/CHUNK)          // 64
#define CD    (DI + 2*DS)         // 2304
#define ROWS  (B_*L_)             // 8192
#define NOUT  (2*DI + 2*DS + NH)  // 4384
#define NPAD  4480                // 35*128

typedef __attribute__((ext_vector_type(4))) float f32x4;
typedef __attribute__((ext_vector_type(8))) __bf16 bf16x8;
typedef __attribute__((ext_vector_type(4))) short s16x4;

// ---------------- conversion kernels ----------------
__global__ __launch_bounds__(256) void k_f32_to_bf16(const float* __restrict__ s, __bf16* __restrict__ d, int n) {
    int i = blockIdx.x * 256 + threadIdx.x;
    if (i < n) d[i] = (__bf16)s[i];
}

__global__ __launch_bounds__(256) void k_convert_pad(const float* __restrict__ s, __bf16* __restrict__ d, int nsrc, int ndst) {
    int i = blockIdx.x * 256 + threadIdx.x;
    if (i < ndst) d[i] = (i < nsrc) ? (__bf16)s[i] : (__bf16)0.f;
}

// ---------------- GEMM core (NT, bf16 MFMA, 128x128 tile, BK=64) ----------------
__device__ __forceinline__ void gemm_core(const __bf16* __restrict__ Ag, const __bf16* __restrict__ Bg,
                                          int K, int m0, int n0,
                                          __bf16* As, __bf16* Bs, f32x4 acc[4][4]) {
    const int tid  = threadIdx.x;
    const int wave = tid >> 6;
    const int lane = tid & 63;
    const int wm   = wave >> 1, wn = wave & 1;
    const int lrow = lane & 15;
    const int lko  = (lane >> 4) * 8;

    for (int kt = 0; kt < K; kt += 64) {
#pragma unroll
        for (int i = 0; i < 4; i++) {
            int e   = (wave * 4 + i) * 512 + lane * 8;
            int row = e >> 6, col = e & 63;
            const __bf16* sa = Ag + (size_t)(m0 + row) * K + kt + col;
            const __bf16* sb = Bg + (size_t)(n0 + row) * K + kt + col;
            __builtin_amdgcn_global_load_lds((const __attribute__((address_space(1))) void*)sa,
                                             (__attribute__((address_space(3))) void*)(As + (wave * 4 + i) * 512),
                                             16, 0, 0);
            __builtin_amdgcn_global_load_lds((const __attribute__((address_space(1))) void*)sb,
                                             (__attribute__((address_space(3))) void*)(Bs + (wave * 4 + i) * 512),
                                             16, 0, 0);
        }
        __syncthreads();
#pragma unroll
        for (int ks = 0; ks < 2; ks++) {
            bf16x8 av[4], bv[4];
#pragma unroll
            for (int mi = 0; mi < 4; mi++)
                av[mi] = *(const bf16x8*)(As + (wm * 64 + mi * 16 + lrow) * 64 + ks * 32 + lko);
#pragma unroll
            for (int ni = 0; ni < 4; ni++)
                bv[ni] = *(const bf16x8*)(Bs + (wn * 64 + ni * 16 + lrow) * 64 + ks * 32 + lko);
#pragma unroll
            for (int mi = 0; mi < 4; mi++)
#pragma unroll
                for (int ni = 0; ni < 4; ni++)
                    acc[mi][ni] = __builtin_amdgcn_mfma_f32_16x16x32_bf16(av[mi], bv[ni], acc[mi][ni], 0, 0, 0);
        }
        __syncthreads();
    }
}

// GEMM1: zxbcdt = u @ W_in^T, fused split + softplus epilogue. 1D grid, XCD-chunked swizzle.
__global__ __launch_bounds__(256) void k_gemm1(const __bf16* __restrict__ ubf, const __bf16* __restrict__ wibf,
                                               __bf16* __restrict__ zbuf, __bf16* __restrict__ xbcraw,
                                               float* __restrict__ dtbuf, const float* __restrict__ dt_bias) {
    __shared__ __align__(16) __bf16 As[128 * 64];
    __shared__ __align__(16) __bf16 Bs[128 * 64];
    f32x4 acc[4][4];
    f32x4 z4 = {0.f, 0.f, 0.f, 0.f};
#pragma unroll
    for (int i = 0; i < 4; i++)
#pragma unroll
        for (int j = 0; j < 4; j++) acc[i][j] = z4;

    // nwg = 64*35 = 2240, 2240/8 = 280 -> bijective chunked XCD swizzle
    int bid = blockIdx.x;
    int wg  = (bid & 7) * 280 + (bid >> 3);
    int m0  = (wg / 35) * 128;
    int n0  = (wg % 35) * 128;
    gemm_core(ubf, wibf, DM, m0, n0, As, Bs, acc);

    const int lane = threadIdx.x & 63, wave = threadIdx.x >> 6;
    const int wm = wave >> 1, wn = wave & 1;
    const int gm_base = m0 + wm * 64 + (lane >> 4) * 4;
    const int gn_base = n0 + wn * 64 + (lane & 15);
#pragma unroll
    for (int mi = 0; mi < 4; mi++)
#pragma unroll
        for (int ni = 0; ni < 4; ni++) {
            int gn = gn_base + ni * 16;
            if (gn >= NOUT) continue;
#pragma unroll
            for (int r = 0; r < 4; r++) {
                int gm = gm_base + mi * 16 + r;
                float v = acc[mi][ni][r];
                if (gn < DI) {
                    zbuf[(size_t)gm * DI + gn] = (__bf16)v;
                } else if (gn < DI + CD) {
                    xbcraw[(size_t)gm * CD + (gn - DI)] = (__bf16)v;
                } else {
                    int hh = gn - (DI + CD);
                    float x = v + dt_bias[hh];
                    float sp = (x > 20.f) ? x : log1pf(__expf(x));
                    dtbuf[(size_t)gm * NH + hh] = sp;
                }
            }
        }
}

// GEMM2: out = ynorm @ W_out^T. 1D grid, XCD-chunked swizzle.
__global__ __launch_bounds__(256) void k_gemm2(const __bf16* __restrict__ ybf, const __bf16* __restrict__ wobf,
                                               float* __restrict__ out) {
    __shared__ __align__(16) __bf16 As[128 * 64];
    __shared__ __align__(16) __bf16 Bs[128 * 64];
    f32x4 acc[4][4];
    f32x4 z4 = {0.f, 0.f, 0.f, 0.f};
#pragma unroll
    for (int i = 0; i < 4; i++)
#pragma unroll
        for (int j = 0; j < 4; j++) acc[i][j] = z4;

    // nwg = 64*8 = 512, 512/8 = 64
    int bid = blockIdx.x;
    int wg  = (bid & 7) * 64 + (bid >> 3);
    int m0  = (wg / 8) * 128;
    int n0  = (wg % 8) * 128;
    gemm_core(ybf, wobf, DI, m0, n0, As, Bs, acc);

    const int lane = threadIdx.x & 63, wave = threadIdx.x >> 6;
    const int wm = wave >> 1, wn = wave & 1;
    const int gm_base = m0 + wm * 64 + (lane >> 4) * 4;
    const int gn_base = n0 + wn * 64 + (lane & 15);
#pragma unroll
    for (int mi = 0; mi < 4; mi++)
#pragma unroll
        for (int ni = 0; ni < 4; ni++) {
            int gn = gn_base + ni * 16;
#pragma unroll
            for (int r = 0; r < 4; r++) {
                int gm = gm_base + mi * 16 + r;
                out[(size_t)gm * DM + gn] = acc[mi][ni][r];
            }
        }
}

// ---------------- depthwise causal conv + SiLU ----------------
__global__ __launch_bounds__(256) void k_conv(const __bf16* __restrict__ xbcraw, const float* __restrict__ conv_w,
                                              const float* __restrict__ conv_b, __bf16* __restrict__ xconv) {
    size_t idx = (size_t)blockIdx.x * 256 + threadIdx.x;
    if (idx >= (size_t)ROWS * CD) return;
    int ch = (int)(idx % CD);
    size_t rem = idx / CD;
    int l = (int)(rem % L_);
    int b = (int)(rem / L_);
    float acc = conv_b[ch];
#pragma unroll
    for (int k = 0; k < 4; k++) {
        int ll = l - 3 + k;
        if (ll >= 0) acc += conv_w[ch * 4 + k] * (float)xbcraw[((size_t)b * L_ + ll) * CD + ch];
    }
    xconv[idx] = (__bf16)(acc / (1.f + __expf(-acc)));  // silu
}

// ---------------- CBT via MFMA: cbt[b][c][i][j] = sum_n C[i][n]*B[j][n] ----------------
__global__ __launch_bounds__(256) void k_cbt(const __bf16* __restrict__ xconv, float* __restrict__ cbt) {
    const int c = blockIdx.x, b = blockIdx.y;
    const int tid = threadIdx.x, wv = tid >> 6, lane = tid & 63;
    const int lrow = lane & 15, lko = (lane >> 4) * 8;
    __shared__ __align__(16) __bf16 Csh[64 * 136];
    __shared__ __align__(16) __bf16 Bsh[64 * 136];
    const size_t rowbase = (size_t)b * L_ + c * CHUNK;
#pragma unroll
    for (int q = 0; q < 32; q++) {
        int i = q * 2 + (wv >> 1);
        int n = (wv & 1) * 64 + lane;
        const __bf16* base = xconv + (rowbase + i) * CD + DI;
        Bsh[i * 136 + n] = base[n];
        Csh[i * 136 + n] = base[DS + n];
    }
    __syncthreads();
    f32x4 acc[4];
    f32x4 z4 = {0.f, 0.f, 0.f, 0.f};
#pragma unroll
    for (int jt = 0; jt < 4; jt++) acc[jt] = z4;
#pragma unroll
    for (int ks = 0; ks < 4; ks++) {
        bf16x8 a = *(const bf16x8*)&Csh[(wv * 16 + lrow) * 136 + ks * 32 + lko];
#pragma unroll
        for (int jt = 0; jt < 4; jt++) {
            bf16x8 bb = *(const bf16x8*)&Bsh[(jt * 16 + lrow) * 136 + ks * 32 + lko];
            acc[jt] = __builtin_amdgcn_mfma_f32_16x16x32_bf16(a, bb, acc[jt], 0, 0, 0);
        }
    }
    float* o = cbt + (size_t)(b * NC + c) * 4096;
#pragma unroll
    for (int jt = 0; jt < 4; jt++)
#pragma unroll
        for (int r = 0; r < 4; r++) {
            int i = wv * 16 + (lane >> 4) * 4 + r;
            int j = jt * 16 + lrow;
            o[i * 64 + j] = acc[jt][r];
        }
}

// ---------------- SSD part A (MFMA): Y_diag + D-skip, chunk states ----------------
__global__ __launch_bounds__(256) void k_ssd_a(const __bf16* __restrict__ xconv, const float* __restrict__ dtbuf,
                                               const float* __restrict__ cbt, const float* __restrict__ A_log,
                                               __bf16* __restrict__ ybuf, __bf16* __restrict__ states,
                                               float* __restrict__ asum, const float* __restrict__ D_param) {
    const int h = blockIdx.x, c = blockIdx.y, b = blockIdx.z;
    const int tid = threadIdx.x, wv = tid >> 6, lane = tid & 63;
    const int lrow = lane & 15, lko = (lane >> 4) * 8;
    __shared__ __align__(16) __bf16 xT[64 * 72];   // xT[p][i] = x[i][p]
    __shared__ __align__(16) __bf16 xsc[64 * 72];  // xT * dcf[i]
    __shared__ __align__(16) __bf16 BT[128 * 72];  // BT[n][i] = B[i][n]
    __shared__ __align__(16) __bf16 Ms[64 * 72];   // masked decay (+ D on diag)
    __shared__ float dts[64], cum[64];

    const float Ah = -__expf(A_log[h]);
    const size_t rowbase = (size_t)b * L_ + c * CHUNK;

    float dtv = 0.f;
    if (wv == 0) { dtv = dtbuf[(rowbase + lane) * NH + h]; dts[lane] = dtv; }
    // x -> xT (transposed store)
#pragma unroll
    for (int q = 0; q < 16; q++) {
        int i = q * 4 + wv;
        xT[lane * 72 + i] = xconv[(rowbase + i) * CD + h * HD + lane];
    }
    // B -> BT
#pragma unroll
    for (int q = 0; q < 32; q++) {
        int i = q * 2 + (wv >> 1);
        int n = (wv & 1) * 64 + lane;
        BT[n * 72 + i] = xconv[(rowbase + i) * CD + DI + n];
    }
    // wave-parallel inclusive scan of Ah*dt
    if (wv == 0) {
        float v = Ah * dtv;
#pragma unroll
        for (int o = 1; o < 64; o <<= 1) { float t = __shfl_up(v, o); if (lane >= o) v += t; }
        cum[lane] = v;
        if (lane == 63) asum[(b * NC + c) * NH + h] = v;
    }
    __syncthreads();

    const float cum63 = cum[63];
    const float Dh = D_param[h];
    const float* cbt_bc = cbt + (size_t)(b * NC + c) * 4096;
#pragma unroll
    for (int q = 0; q < 16; q++) {
        int i = q * 4 + wv, j = lane;
        float cumi = cum[i];
        float m = 0.f;
        if (j <= i) m = cbt_bc[i * 64 + j] * __expf(cumi - cum[j]) * dts[j];
        if (j == i) m += Dh;                     // fold D-skip into diagonal
        Ms[i * 72 + j] = (__bf16)m;
        float dcfi = __expf(cum63 - cumi) * dts[i];
        xsc[lane * 72 + i] = (__bf16)((float)xT[lane * 72 + i] * dcfi);
    }
    __syncthreads();

    f32x4 z4 = {0.f, 0.f, 0.f, 0.f};
    // Y = (M + D*I) @ x : out 64x64, wave wv owns rows 16wv..16wv+15
    {
        f32x4 accY[4];
#pragma unroll
        for (int pt = 0; pt < 4; pt++) accY[pt] = z4;
#pragma unroll
        for (int ks = 0; ks < 2; ks++) {
            bf16x8 a = *(const bf16x8*)&Ms[(wv * 16 + lrow) * 72 + ks * 32 + lko];
#pragma unroll
            for (int pt = 0; pt < 4; pt++) {
                bf16x8 bb = *(const bf16x8*)&xT[(pt * 16 + lrow) * 72 + ks * 32 + lko];
                accY[pt] = __builtin_amdgcn_mfma_f32_16x16x32_bf16(a, bb, accY[pt], 0, 0, 0);
            }
        }
#pragma unroll
        for (int pt = 0; pt < 4; pt++)
#pragma unroll
            for (int r = 0; r < 4; r++) {
                int i = wv * 16 + (lane >> 4) * 4 + r;
                int p = pt * 16 + lrow;
                ybuf[(rowbase + i) * DI + h * HD + p] = (__bf16)accY[pt][r];
            }
    }
    // state[p][n] = sum_i xsc[p][i] * BT[n][i] : out 64x128, wave wv owns p-rows 16wv..
    {
        f32x4 accS[8];
#pragma unroll
        for (int nt = 0; nt < 8; nt++) accS[nt] = z4;
#pragma unroll
        for (int ks = 0; ks < 2; ks++) {
            bf16x8 a = *(const bf16x8*)&xsc[(wv * 16 + lrow) * 72 + ks * 32 + lko];
#pragma unroll
            for (int nt = 0; nt < 8; nt++) {
                bf16x8 bb = *(const bf16x8*)&BT[(nt * 16 + lrow) * 72 + ks * 32 + lko];
                accS[nt] = __builtin_amdgcn_mfma_f32_16x16x32_bf16(a, bb, accS[nt], 0, 0, 0);
            }
        }
        __bf16* sp = states + ((size_t)(b * NC + c) * NH + h) * 8192;
#pragma unroll
        for (int nt = 0; nt < 8; nt++)
#pragma unroll
            for (int r = 0; r < 4; r++) {
                int p = wv * 16 + (lane >> 4) * 4 + r;
                int n = nt * 16 + lrow;
                sp[p * 128 + n] = (__bf16)accS[nt][r];
            }
    }
}

// ---------------- inter-chunk scan (in-place: chunk_states -> states_prev) ----------------
__global__ __launch_bounds__(256) void k_scan(__bf16* __restrict__ states, const float* __restrict__ asum) {
    const int seg = blockIdx.x, h = blockIdx.y, b = blockIdx.z;
    const int e0 = seg * 1024 + threadIdx.x * 4;
    float S[4] = {0.f, 0.f, 0.f, 0.f};
    for (int c = 0; c < NC; c++) {
        float ef = __expf(asum[(b * NC + c) * NH + h]);
        __bf16* ptr = states + (((size_t)(b * NC + c) * NH + h) * 8192) + e0;
        s16x4 raw = *(const s16x4*)ptr;
        s16x4 outv;
#pragma unroll
        for (int q = 0; q < 4; q++) {
            float t = (float)__builtin_bit_cast(__bf16, (short)raw[q]);
            outv[q] = __builtin_bit_cast(short, (__bf16)S[q]);
            S[q] = ef * S[q] + t;
        }
        *(s16x4*)ptr = outv;
    }
}

// ---------------- SSD part B (MFMA): Y += exp(cum[i]) * C @ Sprev^T ----------------
__global__ __launch_bounds__(256) void k_ssd_b(const __bf16* __restrict__ xconv, const float* __restrict__ dtbuf,
                                               const __bf16* __restrict__ states, const float* __restrict__ A_log,
                                               __bf16* __restrict__ ybuf) {
    const int h = blockIdx.x, c = blockIdx.y, b = blockIdx.z;
    const int tid = threadIdx.x, wv = tid >> 6, lane = tid & 63;
    const int lrow = lane & 15, lko = (lane >> 4) * 8;
    __shared__ __align__(16) __bf16 Csh[64 * 136];  // C[i][n]
    __shared__ __align__(16) __bf16 Sps[64 * 136];  // Sprev[p][n]
    __shared__ float cum[64];

    const float Ah = -__expf(A_log[h]);
    const size_t rowbase = (size_t)b * L_ + c * CHUNK;
    const __bf16* sp = states + ((size_t)(b * NC + c) * NH + h) * 8192;
#pragma unroll
    for (int q = 0; q < 32; q++) {
        int i = q * 2 + (wv >> 1);
        int n = (wv & 1) * 64 + lane;
        Csh[i * 136 + n] = xconv[(rowbase + i) * CD + DI + DS + n];
        Sps[i * 136 + n] = sp[i * 128 + n];
    }
    if (wv == 0) {
        float v = Ah * dtbuf[(rowbase + lane) * NH + h];
#pragma unroll
        for (int o = 1; o < 64; o <<= 1) { float t = __shfl_up(v, o); if (lane >= o) v += t; }
        cum[lane] = v;
    }
    __syncthreads();

    f32x4 acc[4];
    f32x4 z4 = {0.f, 0.f, 0.f, 0.f};
#pragma unroll
    for (int pt = 0; pt < 4; pt++) acc[pt] = z4;
#pragma unroll
    for (int ks = 0; ks < 4; ks++) {
        bf16x8 a = *(const bf16x8*)&Csh[(wv * 16 + lrow) * 136 + ks * 32 + lko];
#pragma unroll
        for (int pt = 0; pt < 4; pt++) {
            bf16x8 bb = *(const bf16x8*)&Sps[(pt * 16 + lrow) * 136 + ks * 32 + lko];
            acc[pt] = __builtin_amdgcn_mfma_f32_16x16x32_bf16(a, bb, acc[pt], 0, 0, 0);
        }
    }
#pragma unroll
    for (int r = 0; r < 4; r++) {
        int i = wv * 16 + (lane >> 4) * 4 + r;
        float ef = __expf(cum[i]);
#pragma unroll
        for (int pt = 0; pt < 4; pt++) {
            size_t idx = (rowbase + i) * DI + h * HD + pt * 16 + lrow;
            float y0 = (float)ybuf[idx];
            ybuf[idx] = (__bf16)(y0 + ef * acc[pt][r]);
        }
    }
}

// ---------------- gate (silu(z)) + RMSNorm -> bf16 ----------------
__global__ __launch_bounds__(256) void k_gate_norm(const __bf16* __restrict__ ybuf, const __bf16* __restrict__ zbuf,
                                                   const float* __restrict__ norm_w, __bf16* __restrict__ ybf) {
    const int r = blockIdx.x;
    const int tid = threadIdx.x;
    float v[8];
    float ss = 0.f;
#pragma unroll
    for (int q = 0; q < 8; q++) {
        int col = q * 256 + tid;
        float y = (float)ybuf[(size_t)r * DI + col];
        float z = (float)zbuf[(size_t)r * DI + col];
        float g = z / (1.f + __expf(-z));
        float val = y * g;
        v[q] = val;
        ss += val * val;
    }
#pragma unroll
    for (int o = 32; o > 0; o >>= 1) ss += __shfl_down(ss, o);
    __shared__ float wsum[4];
    __shared__ float rmss;
    if ((tid & 63) == 0) wsum[tid >> 6] = ss;
    __syncthreads();
    if (tid == 0) {
        float t = wsum[0] + wsum[1] + wsum[2] + wsum[3];
        rmss = rsqrtf(t / (float)DI + 1e-5f);
    }
    __syncthreads();
    float rm = rmss;
#pragma unroll
    for (int q = 0; q < 8; q++) {
        int col = q * 256 + tid;
        ybf[(size_t)r * DI + col] = (__bf16)(v[q] * rm * norm_w[col]);
    }
}

// ---------------- launcher ----------------
extern "C" void kernel_launch(void* const* d_in, const int* in_sizes, int n_in,
                              void* d_out, int out_size, void* d_ws, size_t ws_size,
                              hipStream_t stream) {
    const float* u       = (const float*)d_in[0];
    const float* W_in    = (const float*)d_in[1];
    const float* conv_w  = (const float*)d_in[2];
    const float* conv_b  = (const float*)d_in[3];
    const float* dt_bias = (const float*)d_in[4];
    const float* A_log   = (const float*)d_in[5];
    const float* D_param = (const float*)d_in[6];
    const float* norm_w  = (const float*)d_in[7];
    const float* W_out   = (const float*)d_in[8];
    float* out = (float*)d_out;

    // ---- static workspace plan (145.8 MB total) ----
    constexpr size_t OFF_WOBF  = 0;
    constexpr size_t OFF_ZBUF  = 4194304;
    constexpr size_t OFF_DT    = 37748736;
    constexpr size_t OFF_ASUM  = 38797312;
    constexpr size_t OFF_XCONV = 38813696;
    constexpr size_t OFF_CBT   = 76562432;
    constexpr size_t OFF_BIG   = 78659584;
    constexpr size_t NEED      = 145768448;
    if (ws_size < NEED) return;

    char* ws = (char*)d_ws;
    __bf16* wobf   = (__bf16*)(ws + OFF_WOBF);
    __bf16* zbuf   = (__bf16*)(ws + OFF_ZBUF);
    float*  dtbuf  = (float*) (ws + OFF_DT);
    float*  asum   = (float*) (ws + OFF_ASUM);
    __bf16* xconv  = (__bf16*)(ws + OFF_XCONV);
    float*  cbt    = (float*) (ws + OFF_CBT);
    __bf16* ubf    = (__bf16*)(ws + OFF_BIG);
    __bf16* wibf   = (__bf16*)(ws + OFF_BIG + 16777216);
    __bf16* xbcraw = (__bf16*)(ws + OFF_BIG + 25952256);
    __bf16* states = (__bf16*)(ws + OFF_BIG);          // reuses ubf/wibf/xbcraw after conv
    __bf16* ybf    = (__bf16*)(ws + OFF_XCONV);        // reuses xconv after ssd_b
    __bf16* ybuf   = (__bf16*)d_out;                   // bf16 scratch, overwritten by gemm2

    k_f32_to_bf16<<<(ROWS * DM + 255) / 256, 256, 0, stream>>>(u, ubf, ROWS * DM);
    k_convert_pad<<<(NPAD * DM + 255) / 256, 256, 0, stream>>>(W_in, wibf, NOUT * DM, NPAD * DM);
    k_f32_to_bf16<<<(DM * DI + 255) / 256, 256, 0, stream>>>(W_out, wobf, DM * DI);

    k_gemm1<<<2240, 256, 0, stream>>>(ubf, wibf, zbuf, xbcraw, dtbuf, dt_bias);
    k_conv<<<(int)(((size_t)ROWS * CD + 255) / 256), 256, 0, stream>>>(xbcraw, conv_w, conv_b, xconv);
    k_cbt<<<dim3(NC, B_), 256, 0, stream>>>(xconv, cbt);
    k_ssd_a<<<dim3(NH, NC, B_), 256, 0, stream>>>(xconv, dtbuf, cbt, A_log, ybuf, states, asum, D_param);
    k_scan<<<dim3(8, NH, B_), 256, 0, stream>>>(states, asum);
    k_ssd_b<<<dim3(NH, NC, B_), 256, 0, stream>>>(xconv, dtbuf, states, A_log, ybuf);
    k_gate_norm<<<ROWS, 256, 0, stream>>>(ybuf, zbuf, norm_w, ybf);
    k_gemm2<<<512, 256, 0, stream>>>(ybf, wobf, out);
}

// Round 4
// 420.056 us; speedup vs baseline: 1.3626x; 1.0545x over previous
//
#include <hip/hip_runtime.h>
#include <hip/hip_bf16.h>
#include <math.h>

#define B_    2
#define L_    4096
#define DM    1024
#define DI    2048
#define DS    128
#define NH    32
#define HD    64
#define CHUNK 64
#define NC    (L_/CHUNK)          // 64
#define CD    (DI + 2*DS)         // 2304
#define ROWS  (B_*L_)             // 8192
#define NOUT  (2*DI + 2*DS + NH)  // 4384
#define NPAD2 4608                // 18*256, padded N for 256-wide tiles

typedef __attribute__((ext_vector_type(4))) float f32x4;
typedef __attribute__((ext_vector_type(8))) __bf16 bf16x8;
typedef __attribute__((ext_vector_type(4))) short s16x4;

// ---------------- conversion kernels ----------------
__global__ __launch_bounds__(256) void k_f32_to_bf16(const float* __restrict__ s, __bf16* __restrict__ d, int n) {
    int i = blockIdx.x * 256 + threadIdx.x;
    if (i < n) d[i] = (__bf16)s[i];
}

__global__ __launch_bounds__(256) void k_convert_pad(const float* __restrict__ s, __bf16* __restrict__ d, int nsrc, int ndst) {
    int i = blockIdx.x * 256 + threadIdx.x;
    if (i < ndst) d[i] = (i < nsrc) ? (__bf16)s[i] : (__bf16)0.f;
}

// =====================================================================
// 256x256 8-phase GEMM core (NT, bf16 MFMA), BK=64, 8 waves, 128KiB LDS.
// Phases = C-quadrants: each phase needs exactly one A-half + one B-half.
// Quadrant order: (mh,nh) = (0,0),(0,1),(1,1),(1,0).
// Stage order (consumption order of K-tile t+1): A0, B0, B1, A1.
// Counted vmcnt(4) gates at end of phases 0,1,3 (never drain to 0).
// T2 LDS swizzle: phys = logical ^ ((row&7)<<4); applied by inverse-
// swizzling the GLOBAL source (gload_lds dest stays linear) + swizzled
// ds_read address. Half-tile = 128 rows x 64 cols bf16 = 16 KiB.
// =====================================================================
__device__ __forceinline__ void gemm256_core(const __bf16* __restrict__ Ag, const __bf16* __restrict__ Bg,
                                             int K, int m0, int n0, char* lds, f32x4 acc[4][4][2]) {
    const int tid  = threadIdx.x;
    const int wave = tid >> 6;
    const int lane = tid & 63;
    const int wmq  = wave >> 2;          // 0..1 : wave M-pos within quadrant (2x4 wave grid)
    const int wnq  = wave & 3;           // 0..3 : wave N-pos within quadrant
    const int lrow = lane & 15;
    const int KT   = K >> 6;

    // half-tile LDS byte offsets: buf p in [p*65536, +65536)
    auto Ahalf = [](int p, int mh) { return p * 65536 + mh * 16384; };
    auto Bhalf = [](int p, int nh) { return p * 65536 + 32768 + nh * 16384; };

    // stage one half-tile (128x64 bf16) from G rows [grow0, +128), cols [kt, +64)
    auto stage = [&](const __bf16* __restrict__ G, int grow0, int kt, int ldsoff) {
#pragma unroll
        for (int issue = 0; issue < 2; issue++) {
            int o   = issue * 8192 + tid * 16;                 // linear byte offset in half-tile
            int row = o >> 7;                                  // 128 B per row
            int cb  = (o & 127) ^ ((row & 7) << 4);            // inverse swizzle on source
            const __bf16* src = G + (size_t)(grow0 + row) * K + kt + (cb >> 1);
            char* ldsbase = lds + ldsoff + issue * 8192 + wave * 1024;  // wave-uniform
            __builtin_amdgcn_global_load_lds((const __attribute__((address_space(1))) void*)src,
                                             (__attribute__((address_space(3))) void*)ldsbase,
                                             16, 0, 0);
        }
    };
    // read one MFMA fragment (bf16x8) at half-tile row r, kslice ks, with swizzle
    auto rdfrag = [&](int ldsoff, int r, int ks) -> bf16x8 {
        int logical = r * 128 + ks * 64 + ((lane >> 4) << 4);
        int phys    = logical ^ ((r & 7) << 4);
        return *(const bf16x8*)(lds + ldsoff + phys);
    };

    // prologue: stage K-tile 0 in consumption order
    stage(Ag, m0,       0, Ahalf(0, 0));
    stage(Bg, n0,       0, Bhalf(0, 0));
    stage(Bg, n0 + 128, 0, Bhalf(0, 1));
    stage(Ag, m0 + 128, 0, Ahalf(0, 1));
    asm volatile("s_waitcnt vmcnt(4)" ::: "memory");   // A0,B0 of K-tile 0 resident
    __builtin_amdgcn_s_barrier();

    bf16x8 a[4][2], b[2][2];
    for (int t = 0; t < KT; t++) {
        const int p = t & 1, pn = p ^ 1;
        const int kt_next = (t + 1) << 6;
        const bool do_stage = (t + 1 < KT);
#pragma unroll
        for (int q = 0; q < 4; q++) {
            const int mh = q >> 1;
            const int nh = (q & 1) ^ (q >> 1);
            // 1. ds_reads for this quadrant (A reload at q=0,2; B at q=0,1,3)
            if (q == 0 || q == 2) {
                const int ao = Ahalf(p, mh);
#pragma unroll
                for (int fm = 0; fm < 4; fm++)
#pragma unroll
                    for (int ks = 0; ks < 2; ks++)
                        a[fm][ks] = rdfrag(ao, wmq * 64 + fm * 16 + lrow, ks);
            }
            if (q != 2) {
                const int bo = Bhalf(p, nh);
#pragma unroll
                for (int fn = 0; fn < 2; fn++)
#pragma unroll
                    for (int ks = 0; ks < 2; ks++)
                        b[fn][ks] = rdfrag(bo, wnq * 32 + fn * 16 + lrow, ks);
            }
            // 2. stage one half-tile of K-tile t+1 (consumption order A0,B0,B1,A1)
            if (do_stage) {
                if (q == 0)      stage(Ag, m0,       kt_next, Ahalf(pn, 0));
                else if (q == 1) stage(Bg, n0,       kt_next, Bhalf(pn, 0));
                else if (q == 2) stage(Bg, n0 + 128, kt_next, Bhalf(pn, 1));
                else             stage(Ag, m0 + 128, kt_next, Ahalf(pn, 1));
            }
            // 3. barrier A (align waves for the MFMA cluster)
            __builtin_amdgcn_s_barrier();
            // 4. MFMA cluster (16), setprio wrapped
            __builtin_amdgcn_s_setprio(1);
#pragma unroll
            for (int fm = 0; fm < 4; fm++)
#pragma unroll
                for (int fn = 0; fn < 2; fn++)
#pragma unroll
                    for (int ks = 0; ks < 2; ks++)
                        acc[q][fm][fn] = __builtin_amdgcn_mfma_f32_16x16x32_bf16(a[fm][ks], b[fn][ks], acc[q][fm][fn], 0, 0, 0);
            __builtin_amdgcn_s_setprio(0);
            // 5. counted gate for next phase's fresh half-tile (end of ph0,ph1,ph3)
            if (q != 2) asm volatile("s_waitcnt vmcnt(4)" ::: "memory");
            // 6. barrier B
            __builtin_amdgcn_s_barrier();
        }
    }
}

// GEMM1: zxbcdt = u @ W_in^T, fused split + softplus epilogue.
__global__ __launch_bounds__(512, 2) void k_gemm1(const __bf16* __restrict__ ubf, const __bf16* __restrict__ wibf,
                                                  __bf16* __restrict__ zbuf, __bf16* __restrict__ xbcraw,
                                                  float* __restrict__ dtbuf, const float* __restrict__ dt_bias) {
    extern __shared__ char lds[];
    f32x4 acc[4][4][2];
    f32x4 z4 = {0.f, 0.f, 0.f, 0.f};
#pragma unroll
    for (int q = 0; q < 4; q++)
#pragma unroll
        for (int i = 0; i < 4; i++)
#pragma unroll
            for (int j = 0; j < 2; j++) acc[q][i][j] = z4;

    // nwg = 32*18 = 576, /8 = 72 -> bijective chunked XCD swizzle; m-major for A-panel L2 reuse
    int bid = blockIdx.x;
    int wg  = (bid & 7) * 72 + (bid >> 3);
    int m0  = (wg / 18) * 256;
    int n0  = (wg % 18) * 256;
    gemm256_core(ubf, wibf, DM, m0, n0, lds, acc);

    const int lane = threadIdx.x & 63, wave = threadIdx.x >> 6;
    const int wmq = wave >> 2, wnq = wave & 3;
#pragma unroll
    for (int q = 0; q < 4; q++) {
        const int mh = q >> 1, nh = (q & 1) ^ (q >> 1);
#pragma unroll
        for (int fm = 0; fm < 4; fm++) {
            const int gmb = m0 + mh * 128 + wmq * 64 + fm * 16 + ((lane >> 4) << 2);
#pragma unroll
            for (int fn = 0; fn < 2; fn++) {
                const int gn = n0 + nh * 128 + wnq * 32 + fn * 16 + (lane & 15);
                if (gn < DI) {
#pragma unroll
                    for (int r = 0; r < 4; r++)
                        zbuf[(size_t)(gmb + r) * DI + gn] = (__bf16)acc[q][fm][fn][r];
                } else if (gn < DI + CD) {
#pragma unroll
                    for (int r = 0; r < 4; r++)
                        xbcraw[(size_t)(gmb + r) * CD + (gn - DI)] = (__bf16)acc[q][fm][fn][r];
                } else if (gn < NOUT) {
                    const int hh = gn - (DI + CD);
                    const float bb = dt_bias[hh];
#pragma unroll
                    for (int r = 0; r < 4; r++) {
                        float x = acc[q][fm][fn][r] + bb;
                        float sp = (x > 20.f) ? x : log1pf(__expf(x));
                        dtbuf[(size_t)(gmb + r) * NH + hh] = sp;
                    }
                }
            }
        }
    }
}

// GEMM2: out = ynorm @ W_out^T
__global__ __launch_bounds__(512, 2) void k_gemm2(const __bf16* __restrict__ ybf, const __bf16* __restrict__ wobf,
                                                  float* __restrict__ out) {
    extern __shared__ char lds[];
    f32x4 acc[4][4][2];
    f32x4 z4 = {0.f, 0.f, 0.f, 0.f};
#pragma unroll
    for (int q = 0; q < 4; q++)
#pragma unroll
        for (int i = 0; i < 4; i++)
#pragma unroll
            for (int j = 0; j < 2; j++) acc[q][i][j] = z4;

    // nwg = 32*4 = 128, /8 = 16
    int bid = blockIdx.x;
    int wg  = (bid & 7) * 16 + (bid >> 3);
    int m0  = (wg / 4) * 256;
    int n0  = (wg % 4) * 256;
    gemm256_core(ybf, wobf, DI, m0, n0, lds, acc);

    const int lane = threadIdx.x & 63, wave = threadIdx.x >> 6;
    const int wmq = wave >> 2, wnq = wave & 3;
#pragma unroll
    for (int q = 0; q < 4; q++) {
        const int mh = q >> 1, nh = (q & 1) ^ (q >> 1);
#pragma unroll
        for (int fm = 0; fm < 4; fm++) {
            const int gmb = m0 + mh * 128 + wmq * 64 + fm * 16 + ((lane >> 4) << 2);
#pragma unroll
            for (int fn = 0; fn < 2; fn++) {
                const int gn = n0 + nh * 128 + wnq * 32 + fn * 16 + (lane & 15);
#pragma unroll
                for (int r = 0; r < 4; r++)
                    out[(size_t)(gmb + r) * DM + gn] = acc[q][fm][fn][r];
            }
        }
    }
}

// ---------------- depthwise causal conv + SiLU ----------------
__global__ __launch_bounds__(256) void k_conv(const __bf16* __restrict__ xbcraw, const float* __restrict__ conv_w,
                                              const float* __restrict__ conv_b, __bf16* __restrict__ xconv) {
    size_t idx = (size_t)blockIdx.x * 256 + threadIdx.x;
    if (idx >= (size_t)ROWS * CD) return;
    int ch = (int)(idx % CD);
    size_t rem = idx / CD;
    int l = (int)(rem % L_);
    int b = (int)(rem / L_);
    float acc = conv_b[ch];
#pragma unroll
    for (int k = 0; k < 4; k++) {
        int ll = l - 3 + k;
        if (ll >= 0) acc += conv_w[ch * 4 + k] * (float)xbcraw[((size_t)b * L_ + ll) * CD + ch];
    }
    xconv[idx] = (__bf16)(acc / (1.f + __expf(-acc)));  // silu
}

// ---------------- CBT via MFMA: cbt[b][c][i][j] = sum_n C[i][n]*B[j][n] ----------------
__global__ __launch_bounds__(256) void k_cbt(const __bf16* __restrict__ xconv, float* __restrict__ cbt) {
    const int c = blockIdx.x, b = blockIdx.y;
    const int tid = threadIdx.x, wv = tid >> 6, lane = tid & 63;
    const int lrow = lane & 15, lko = (lane >> 4) * 8;
    __shared__ __align__(16) __bf16 Csh[64 * 136];
    __shared__ __align__(16) __bf16 Bsh[64 * 136];
    const size_t rowbase = (size_t)b * L_ + c * CHUNK;
#pragma unroll
    for (int q = 0; q < 32; q++) {
        int i = q * 2 + (wv >> 1);
        int n = (wv & 1) * 64 + lane;
        const __bf16* base = xconv + (rowbase + i) * CD + DI;
        Bsh[i * 136 + n] = base[n];
        Csh[i * 136 + n] = base[DS + n];
    }
    __syncthreads();
    f32x4 acc[4];
    f32x4 z4 = {0.f, 0.f, 0.f, 0.f};
#pragma unroll
    for (int jt = 0; jt < 4; jt++) acc[jt] = z4;
#pragma unroll
    for (int ks = 0; ks < 4; ks++) {
        bf16x8 a = *(const bf16x8*)&Csh[(wv * 16 + lrow) * 136 + ks * 32 + lko];
#pragma unroll
        for (int jt = 0; jt < 4; jt++) {
            bf16x8 bb = *(const bf16x8*)&Bsh[(jt * 16 + lrow) * 136 + ks * 32 + lko];
            acc[jt] = __builtin_amdgcn_mfma_f32_16x16x32_bf16(a, bb, acc[jt], 0, 0, 0);
        }
    }
    float* o = cbt + (size_t)(b * NC + c) * 4096;
#pragma unroll
    for (int jt = 0; jt < 4; jt++)
#pragma unroll
        for (int r = 0; r < 4; r++) {
            int i = wv * 16 + (lane >> 4) * 4 + r;
            int j = jt * 16 + lrow;
            o[i * 64 + j] = acc[jt][r];
        }
}

// ---------------- SSD part A (MFMA): Y_diag + D-skip, chunk states ----------------
__global__ __launch_bounds__(256) void k_ssd_a(const __bf16* __restrict__ xconv, const float* __restrict__ dtbuf,
                                               const float* __restrict__ cbt, const float* __restrict__ A_log,
                                               __bf16* __restrict__ ybuf, __bf16* __restrict__ states,
                                               float* __restrict__ asum, const float* __restrict__ D_param) {
    const int h = blockIdx.x, c = blockIdx.y, b = blockIdx.z;
    const int tid = threadIdx.x, wv = tid >> 6, lane = tid & 63;
    const int lrow = lane & 15, lko = (lane >> 4) * 8;
    __shared__ __align__(16) __bf16 xT[64 * 72];   // xT[p][i] = x[i][p]
    __shared__ __align__(16) __bf16 xsc[64 * 72];  // xT * dcf[i]
    __shared__ __align__(16) __bf16 BT[128 * 72];  // BT[n][i] = B[i][n]
    __shared__ __align__(16) __bf16 Ms[64 * 72];   // masked decay (+ D on diag)
    __shared__ float dts[64], cum[64];

    const float Ah = -__expf(A_log[h]);
    const size_t rowbase = (size_t)b * L_ + c * CHUNK;

    float dtv = 0.f;
    if (wv == 0) { dtv = dtbuf[(rowbase + lane) * NH + h]; dts[lane] = dtv; }
#pragma unroll
    for (int q = 0; q < 16; q++) {
        int i = q * 4 + wv;
        xT[lane * 72 + i] = xconv[(rowbase + i) * CD + h * HD + lane];
    }
#pragma unroll
    for (int q = 0; q < 32; q++) {
        int i = q * 2 + (wv >> 1);
        int n = (wv & 1) * 64 + lane;
        BT[n * 72 + i] = xconv[(rowbase + i) * CD + DI + n];
    }
    if (wv == 0) {
        float v = Ah * dtv;
#pragma unroll
        for (int o = 1; o < 64; o <<= 1) { float t = __shfl_up(v, o); if (lane >= o) v += t; }
        cum[lane] = v;
        if (lane == 63) asum[(b * NC + c) * NH + h] = v;
    }
    __syncthreads();

    const float cum63 = cum[63];
    const float Dh = D_param[h];
    const float* cbt_bc = cbt + (size_t)(b * NC + c) * 4096;
#pragma unroll
    for (int q = 0; q < 16; q++) {
        int i = q * 4 + wv, j = lane;
        float cumi = cum[i];
        float m = 0.f;
        if (j <= i) m = cbt_bc[i * 64 + j] * __expf(cumi - cum[j]) * dts[j];
        if (j == i) m += Dh;
        Ms[i * 72 + j] = (__bf16)m;
        float dcfi = __expf(cum63 - cumi) * dts[i];
        xsc[lane * 72 + i] = (__bf16)((float)xT[lane * 72 + i] * dcfi);
    }
    __syncthreads();

    f32x4 z4 = {0.f, 0.f, 0.f, 0.f};
    {
        f32x4 accY[4];
#pragma unroll
        for (int pt = 0; pt < 4; pt++) accY[pt] = z4;
#pragma unroll
        for (int ks = 0; ks < 2; ks++) {
            bf16x8 a = *(const bf16x8*)&Ms[(wv * 16 + lrow) * 72 + ks * 32 + lko];
#pragma unroll
            for (int pt = 0; pt < 4; pt++) {
                bf16x8 bb = *(const bf16x8*)&xT[(pt * 16 + lrow) * 72 + ks * 32 + lko];
                accY[pt] = __builtin_amdgcn_mfma_f32_16x16x32_bf16(a, bb, accY[pt], 0, 0, 0);
            }
        }
#pragma unroll
        for (int pt = 0; pt < 4; pt++)
#pragma unroll
            for (int r = 0; r < 4; r++) {
                int i = wv * 16 + (lane >> 4) * 4 + r;
                int p = pt * 16 + lrow;
                ybuf[(rowbase + i) * DI + h * HD + p] = (__bf16)accY[pt][r];
            }
    }
    {
        f32x4 accS[8];
#pragma unroll
        for (int nt = 0; nt < 8; nt++) accS[nt] = z4;
#pragma unroll
        for (int ks = 0; ks < 2; ks++) {
            bf16x8 a = *(const bf16x8*)&xsc[(wv * 16 + lrow) * 72 + ks * 32 + lko];
#pragma unroll
            for (int nt = 0; nt < 8; nt++) {
                bf16x8 bb = *(const bf16x8*)&BT[(nt * 16 + lrow) * 72 + ks * 32 + lko];
                accS[nt] = __builtin_amdgcn_mfma_f32_16x16x32_bf16(a, bb, accS[nt], 0, 0, 0);
            }
        }
        __bf16* sp = states + ((size_t)(b * NC + c) * NH + h) * 8192;
#pragma unroll
        for (int nt = 0; nt < 8; nt++)
#pragma unroll
            for (int r = 0; r < 4; r++) {
                int p = wv * 16 + (lane >> 4) * 4 + r;
                int n = nt * 16 + lrow;
                sp[p * 128 + n] = (__bf16)accS[nt][r];
            }
    }
}

// ---------------- inter-chunk scan (in-place: chunk_states -> states_prev) ----------------
__global__ __launch_bounds__(256) void k_scan(__bf16* __restrict__ states, const float* __restrict__ asum) {
    const int seg = blockIdx.x, h = blockIdx.y, b = blockIdx.z;
    const int e0 = seg * 1024 + threadIdx.x * 4;
    float S[4] = {0.f, 0.f, 0.f, 0.f};
    for (int c = 0; c < NC; c++) {
        float ef = __expf(asum[(b * NC + c) * NH + h]);
        __bf16* ptr = states + (((size_t)(b * NC + c) * NH + h) * 8192) + e0;
        s16x4 raw = *(const s16x4*)ptr;
        s16x4 outv;
#pragma unroll
        for (int q = 0; q < 4; q++) {
            float t = (float)__builtin_bit_cast(__bf16, (short)raw[q]);
            outv[q] = __builtin_bit_cast(short, (__bf16)S[q]);
            S[q] = ef * S[q] + t;
        }
        *(s16x4*)ptr = outv;
    }
}

// ---------------- SSD part B (MFMA): Y += exp(cum[i]) * C @ Sprev^T ----------------
__global__ __launch_bounds__(256) void k_ssd_b(const __bf16* __restrict__ xconv, const float* __restrict__ dtbuf,
                                               const __bf16* __restrict__ states, const float* __restrict__ A_log,
                                               __bf16* __restrict__ ybuf) {
    const int h = blockIdx.x, c = blockIdx.y, b = blockIdx.z;
    const int tid = threadIdx.x, wv = tid >> 6, lane = tid & 63;
    const int lrow = lane & 15, lko = (lane >> 4) * 8;
    __shared__ __align__(16) __bf16 Csh[64 * 136];
    __shared__ __align__(16) __bf16 Sps[64 * 136];
    __shared__ float cum[64];

    const float Ah = -__expf(A_log[h]);
    const size_t rowbase = (size_t)b * L_ + c * CHUNK;
    const __bf16* sp = states + ((size_t)(b * NC + c) * NH + h) * 8192;
#pragma unroll
    for (int q = 0; q < 32; q++) {
        int i = q * 2 + (wv >> 1);
        int n = (wv & 1) * 64 + lane;
        Csh[i * 136 + n] = xconv[(rowbase + i) * CD + DI + DS + n];
        Sps[i * 136 + n] = sp[i * 128 + n];
    }
    if (wv == 0) {
        float v = Ah * dtbuf[(rowbase + lane) * NH + h];
#pragma unroll
        for (int o = 1; o < 64; o <<= 1) { float t = __shfl_up(v, o); if (lane >= o) v += t; }
        cum[lane] = v;
    }
    __syncthreads();

    f32x4 acc[4];
    f32x4 z4 = {0.f, 0.f, 0.f, 0.f};
#pragma unroll
    for (int pt = 0; pt < 4; pt++) acc[pt] = z4;
#pragma unroll
    for (int ks = 0; ks < 4; ks++) {
        bf16x8 a = *(const bf16x8*)&Csh[(wv * 16 + lrow) * 136 + ks * 32 + lko];
#pragma unroll
        for (int pt = 0; pt < 4; pt++) {
            bf16x8 bb = *(const bf16x8*)&Sps[(pt * 16 + lrow) * 136 + ks * 32 + lko];
            acc[pt] = __builtin_amdgcn_mfma_f32_16x16x32_bf16(a, bb, acc[pt], 0, 0, 0);
        }
    }
#pragma unroll
    for (int r = 0; r < 4; r++) {
        int i = wv * 16 + (lane >> 4) * 4 + r;
        float ef = __expf(cum[i]);
#pragma unroll
        for (int pt = 0; pt < 4; pt++) {
            size_t idx = (rowbase + i) * DI + h * HD + pt * 16 + lrow;
            float y0 = (float)ybuf[idx];
            ybuf[idx] = (__bf16)(y0 + ef * acc[pt][r]);
        }
    }
}

// ---------------- gate (silu(z)) + RMSNorm -> bf16 ----------------
__global__ __launch_bounds__(256) void k_gate_norm(const __bf16* __restrict__ ybuf, const __bf16* __restrict__ zbuf,
                                                   const float* __restrict__ norm_w, __bf16* __restrict__ ybf) {
    const int r = blockIdx.x;
    const int tid = threadIdx.x;
    float v[8];
    float ss = 0.f;
#pragma unroll
    for (int q = 0; q < 8; q++) {
        int col = q * 256 + tid;
        float y = (float)ybuf[(size_t)r * DI + col];
        float z = (float)zbuf[(size_t)r * DI + col];
        float g = z / (1.f + __expf(-z));
        float val = y * g;
        v[q] = val;
        ss += val * val;
    }
#pragma unroll
    for (int o = 32; o > 0; o >>= 1) ss += __shfl_down(ss, o);
    __shared__ float wsum[4];
    __shared__ float rmss;
    if ((tid & 63) == 0) wsum[tid >> 6] = ss;
    __syncthreads();
    if (tid == 0) {
        float t = wsum[0] + wsum[1] + wsum[2] + wsum[3];
        rmss = rsqrtf(t / (float)DI + 1e-5f);
    }
    __syncthreads();
    float rm = rmss;
#pragma unroll
    for (int q = 0; q < 8; q++) {
        int col = q * 256 + tid;
        ybf[(size_t)r * DI + col] = (__bf16)(v[q] * rm * norm_w[col]);
    }
}

// ---------------- launcher ----------------
extern "C" void kernel_launch(void* const* d_in, const int* in_sizes, int n_in,
                              void* d_out, int out_size, void* d_ws, size_t ws_size,
                              hipStream_t stream) {
    const float* u       = (const float*)d_in[0];
    const float* W_in    = (const float*)d_in[1];
    const float* conv_w  = (const float*)d_in[2];
    const float* conv_b  = (const float*)d_in[3];
    const float* dt_bias = (const float*)d_in[4];
    const float* A_log   = (const float*)d_in[5];
    const float* D_param = (const float*)d_in[6];
    const float* norm_w  = (const float*)d_in[7];
    const float* W_out   = (const float*)d_in[8];
    float* out = (float*)d_out;

    // ---- static workspace plan (145.8 MB total) ----
    constexpr size_t OFF_WOBF  = 0;
    constexpr size_t OFF_ZBUF  = 4194304;
    constexpr size_t OFF_DT    = 37748736;
    constexpr size_t OFF_ASUM  = 38797312;
    constexpr size_t OFF_XCONV = 38813696;
    constexpr size_t OFF_CBT   = 76562432;
    constexpr size_t OFF_BIG   = 78659584;
    constexpr size_t NEED      = 145768448;
    if (ws_size < NEED) return;

    char* ws = (char*)d_ws;
    __bf16* wobf   = (__bf16*)(ws + OFF_WOBF);
    __bf16* zbuf   = (__bf16*)(ws + OFF_ZBUF);
    float*  dtbuf  = (float*) (ws + OFF_DT);
    float*  asum   = (float*) (ws + OFF_ASUM);
    __bf16* xconv  = (__bf16*)(ws + OFF_XCONV);
    float*  cbt    = (float*) (ws + OFF_CBT);
    __bf16* ubf    = (__bf16*)(ws + OFF_BIG);                        // 16,777,216 B
    __bf16* wibf   = (__bf16*)(ws + OFF_BIG + 16777216);             //  9,437,184 B (4608x1024 bf16)
    __bf16* xbcraw = (__bf16*)(ws + OFF_BIG + 16777216 + 9437184);   // 37,748,736 B
    __bf16* states = (__bf16*)(ws + OFF_BIG);                        // 67,108,864 B (after conv)
    __bf16* ybf    = (__bf16*)(ws + OFF_XCONV);                      // reuses xconv after ssd_b
    __bf16* ybuf   = (__bf16*)d_out;                                 // bf16 scratch, overwritten by gemm2

    // allow 128 KiB dynamic LDS on the 8-phase GEMMs (idempotent, graph-safe)
    (void)hipFuncSetAttribute((const void*)k_gemm1, hipFuncAttributeMaxDynamicSharedMemorySize, 131072);
    (void)hipFuncSetAttribute((const void*)k_gemm2, hipFuncAttributeMaxDynamicSharedMemorySize, 131072);

    k_f32_to_bf16<<<(ROWS * DM + 255) / 256, 256, 0, stream>>>(u, ubf, ROWS * DM);
    k_convert_pad<<<(NPAD2 * DM + 255) / 256, 256, 0, stream>>>(W_in, wibf, NOUT * DM, NPAD2 * DM);
    k_f32_to_bf16<<<(DM * DI + 255) / 256, 256, 0, stream>>>(W_out, wobf, DM * DI);

    k_gemm1<<<576, 512, 131072, stream>>>(ubf, wibf, zbuf, xbcraw, dtbuf, dt_bias);
    k_conv<<<(int)(((size_t)ROWS * CD + 255) / 256), 256, 0, stream>>>(xbcraw, conv_w, conv_b, xconv);
    k_cbt<<<dim3(NC, B_), 256, 0, stream>>>(xconv, cbt);
    k_ssd_a<<<dim3(NH, NC, B_), 256, 0, stream>>>(xconv, dtbuf, cbt, A_log, ybuf, states, asum, D_param);
    k_scan<<<dim3(8, NH, B_), 256, 0, stream>>>(states, asum);
    k_ssd_b<<<dim3(NH, NC, B_), 256, 0, stream>>>(xconv, dtbuf, states, A_log, ybuf);
    k_gate_norm<<<ROWS, 256, 0, stream>>>(ybuf, zbuf, norm_w, ybf);
    k_gemm2<<<128, 512, 131072, stream>>>(ybf, wobf, out);
}

// Round 5
// 409.056 us; speedup vs baseline: 1.3992x; 1.0269x over previous
//
#include <hip/hip_runtime.h>
#include <hip/hip_bf16.h>
#include <math.h>

#define B_    2
#define L_    4096
#define DM    1024
#define DI    2048
#define DS    128
#define NH    32
#define HD    64
#define CHUNK 64
#define NC    (L_/CHUNK)          // 64
#define CD    (DI + 2*DS)         // 2304
#define ROWS  (B_*L_)             // 8192
#define NOUT  (2*DI + 2*DS + NH)  // 4384
#define NPAD2 4608                // 18*256

typedef __attribute__((ext_vector_type(4))) float f32x4;
typedef __attribute__((ext_vector_type(8))) __bf16 bf16x8;
typedef __attribute__((ext_vector_type(4))) short s16x4;

// ---------------- conversion kernels ----------------
__global__ __launch_bounds__(256) void k_f32_to_bf16(const float* __restrict__ s, __bf16* __restrict__ d, int n) {
    int i = blockIdx.x * 256 + threadIdx.x;
    if (i < n) d[i] = (__bf16)s[i];
}

__global__ __launch_bounds__(256) void k_convert_pad(const float* __restrict__ s, __bf16* __restrict__ d, int nsrc, int ndst) {
    int i = blockIdx.x * 256 + threadIdx.x;
    if (i < ndst) d[i] = (i < nsrc) ? (__bf16)s[i] : (__bf16)0.f;
}

// ---------------- shared staging / read helpers (swizzled half-tiles) ----------------
// half-tile = 128 rows x 64 cols bf16 (16 KiB). T2 swizzle: phys_byte = logical ^ ((row&7)<<4),
// applied via inverse-swizzled GLOBAL source (gload_lds dest stays wave-linear) + swizzled ds_read.
__device__ __forceinline__ void stage_half(const __bf16* __restrict__ G, int ldg, int grow0, int kt,
                                           char* lds, int ldsoff, int tid, int wave) {
#pragma unroll
    for (int issue = 0; issue < 2; issue++) {
        int o   = issue * 8192 + tid * 16;
        int row = o >> 7;
        int cb  = (o & 127) ^ ((row & 7) << 4);
        const __bf16* src = G + (size_t)(grow0 + row) * ldg + kt + (cb >> 1);
        char* ldsbase = lds + ldsoff + issue * 8192 + wave * 1024;
        __builtin_amdgcn_global_load_lds((const __attribute__((address_space(1))) void*)src,
                                         (__attribute__((address_space(3))) void*)ldsbase,
                                         16, 0, 0);
    }
}

__device__ __forceinline__ bf16x8 rdfrag(const char* lds, int ldsoff, int r, int ks, int lane) {
    int logical = r * 128 + ks * 64 + ((lane >> 4) << 4);
    int phys    = logical ^ ((r & 7) << 4);
    return *(const bf16x8*)(lds + ldsoff + phys);
}

// =====================================================================
// 256x256 4-quadrant-phase GEMM core, BK=64, 8 waves, 128 KiB LDS, dbuf.
// Deep staging: K-tile t+1's 4 half-tiles staged in phases 0-1 of tile t
// (2 halves each) -> every gated load has >=3 phases of slack.
// Gates (steady): vmcnt(6)@end-ph0, vmcnt(8)@end-ph1, vmcnt(4)@end-ph3.
// Tail (last tile): vmcnt(2)@ph0, vmcnt(0)@ph1, none@ph3.
// =====================================================================
__device__ __forceinline__ void gemm256_core(const __bf16* __restrict__ Ag, const __bf16* __restrict__ Bg,
                                             int K, int m0, int n0, char* lds, f32x4 acc[4][4][2]) {
    const int tid  = threadIdx.x;
    const int wave = tid >> 6;
    const int lane = tid & 63;
    const int wmq  = wave >> 2;
    const int wnq  = wave & 3;
    const int lrow = lane & 15;
    const int KT   = K >> 6;

    auto Ahalf = [](int p, int mh) { return p * 65536 + mh * 16384; };
    auto Bhalf = [](int p, int nh) { return p * 65536 + 32768 + nh * 16384; };

    // prologue: stage K-tile 0 fully
    stage_half(Ag, K, m0,       0, lds, Ahalf(0, 0), tid, wave);
    stage_half(Bg, K, n0,       0, lds, Bhalf(0, 0), tid, wave);
    stage_half(Bg, K, n0 + 128, 0, lds, Bhalf(0, 1), tid, wave);
    stage_half(Ag, K, m0 + 128, 0, lds, Ahalf(0, 1), tid, wave);
    asm volatile("s_waitcnt vmcnt(4)" ::: "memory");
    __builtin_amdgcn_s_barrier();

    bf16x8 a[4][2], b[2][2];
    for (int t = 0; t < KT; t++) {
        const int p = t & 1, pn = p ^ 1;
        const int kn = (t + 1) << 6;
        const bool ds = (t + 1 < KT);
#pragma unroll
        for (int q = 0; q < 4; q++) {
            const int mh = q >> 1;
            const int nh = (q & 1) ^ (q >> 1);
            if (q == 0 || q == 2) {
                const int ao = Ahalf(p, mh);
#pragma unroll
                for (int fm = 0; fm < 4; fm++)
#pragma unroll
                    for (int ks = 0; ks < 2; ks++)
                        a[fm][ks] = rdfrag(lds, ao, wmq * 64 + fm * 16 + lrow, ks, lane);
            }
            if (q != 2) {
                const int bo = Bhalf(p, nh);
#pragma unroll
                for (int fn = 0; fn < 2; fn++)
#pragma unroll
                    for (int ks = 0; ks < 2; ks++)
                        b[fn][ks] = rdfrag(lds, bo, wnq * 32 + fn * 16 + lrow, ks, lane);
            }
            if (ds) {
                if (q == 0) {
                    stage_half(Ag, K, m0,       kn, lds, Ahalf(pn, 0), tid, wave);
                    stage_half(Bg, K, n0,       kn, lds, Bhalf(pn, 0), tid, wave);
                } else if (q == 1) {
                    stage_half(Bg, K, n0 + 128, kn, lds, Bhalf(pn, 1), tid, wave);
                    stage_half(Ag, K, m0 + 128, kn, lds, Ahalf(pn, 1), tid, wave);
                }
            }
            __builtin_amdgcn_s_barrier();
            __builtin_amdgcn_s_setprio(1);
#pragma unroll
            for (int fm = 0; fm < 4; fm++)
#pragma unroll
                for (int fn = 0; fn < 2; fn++)
#pragma unroll
                    for (int ks = 0; ks < 2; ks++)
                        acc[q][fm][fn] = __builtin_amdgcn_mfma_f32_16x16x32_bf16(a[fm][ks], b[fn][ks], acc[q][fm][fn], 0, 0, 0);
            __builtin_amdgcn_s_setprio(0);
            if (q == 0) {
                if (ds) asm volatile("s_waitcnt vmcnt(6)" ::: "memory");
                else    asm volatile("s_waitcnt vmcnt(2)" ::: "memory");
            } else if (q == 1) {
                if (ds) asm volatile("s_waitcnt vmcnt(8)" ::: "memory");
                else    asm volatile("s_waitcnt vmcnt(0)" ::: "memory");
            } else if (q == 3) {
                if (ds) asm volatile("s_waitcnt vmcnt(4)" ::: "memory");
            }
            __builtin_amdgcn_s_barrier();
        }
    }
}

// =====================================================================
// 256x128 2-phase GEMM core, BK=64, 8 waves (2m x 4n, wave-tile 128x32),
// 3-buffer LDS (144 KiB): buf k at k*49152 { A0, A1, B }.
// Stage 2 K-tiles ahead; single gate vmcnt(6) at end of each tile.
// =====================================================================
__device__ __forceinline__ void gemm256x128_core(const __bf16* __restrict__ Ag, const __bf16* __restrict__ Bg,
                                                 int K, int m0, int n0, char* lds, f32x4 acc[8][2]) {
    const int tid  = threadIdx.x;
    const int wave = tid >> 6;
    const int lane = tid & 63;
    const int wmq  = wave >> 2;          // m half (128 rows)
    const int wnq  = wave & 3;           // n quarter (32 cols)
    const int lrow = lane & 15;
    const int KT   = K >> 6;

    auto stage_tile = [&](int t, int buf) {
        const int kt = t << 6;
        stage_half(Ag, K, m0,       kt, lds, buf * 49152,         tid, wave);
        stage_half(Ag, K, m0 + 128, kt, lds, buf * 49152 + 16384, tid, wave);
        stage_half(Bg, K, n0,       kt, lds, buf * 49152 + 32768, tid, wave);
    };

    stage_tile(0, 0);
    if (KT > 1) stage_tile(1, 1);
    asm volatile("s_waitcnt vmcnt(6)" ::: "memory");
    __builtin_amdgcn_s_barrier();

    bf16x8 a[4][2], b[2][2];
    int cur = 0;
    for (int t = 0; t < KT; t++) {
        const int ao = cur * 49152 + wmq * 16384;
        const int bo = cur * 49152 + 32768;
        const bool ds = (t + 2 < KT);
#pragma unroll
        for (int g = 0; g < 2; g++) {
            if (g == 0) {
#pragma unroll
                for (int fn = 0; fn < 2; fn++)
#pragma unroll
                    for (int ks = 0; ks < 2; ks++)
                        b[fn][ks] = rdfrag(lds, bo, wnq * 32 + fn * 16 + lrow, ks, lane);
            }
#pragma unroll
            for (int fm = 0; fm < 4; fm++)
#pragma unroll
                for (int ks = 0; ks < 2; ks++)
                    a[fm][ks] = rdfrag(lds, ao, g * 64 + fm * 16 + lrow, ks, lane);
            if (g == 0 && ds) {
                int b2 = cur + 2; if (b2 >= 3) b2 -= 3;
                stage_tile(t + 2, b2);
            }
            __builtin_amdgcn_s_barrier();
            __builtin_amdgcn_s_setprio(1);
#pragma unroll
            for (int fm = 0; fm < 4; fm++)
#pragma unroll
                for (int fn = 0; fn < 2; fn++)
#pragma unroll
                    for (int ks = 0; ks < 2; ks++)
                        acc[g * 4 + fm][fn] = __builtin_amdgcn_mfma_f32_16x16x32_bf16(a[fm][ks], b[fn][ks], acc[g * 4 + fm][fn], 0, 0, 0);
            __builtin_amdgcn_s_setprio(0);
            if (g == 1 && t + 1 < KT) {
                if (ds) asm volatile("s_waitcnt vmcnt(6)" ::: "memory");
                else    asm volatile("s_waitcnt vmcnt(0)" ::: "memory");
            }
            __builtin_amdgcn_s_barrier();
        }
        cur = (cur == 2) ? 0 : cur + 1;
    }
}

// GEMM1: zxbcdt = u @ W_in^T, fused split + softplus epilogue.
__global__ __launch_bounds__(512, 2) void k_gemm1(const __bf16* __restrict__ ubf, const __bf16* __restrict__ wibf,
                                                  __bf16* __restrict__ zbuf, __bf16* __restrict__ xbcraw,
                                                  float* __restrict__ dtbuf, const float* __restrict__ dt_bias) {
    extern __shared__ char lds[];
    f32x4 acc[4][4][2];
    f32x4 z4 = {0.f, 0.f, 0.f, 0.f};
#pragma unroll
    for (int q = 0; q < 4; q++)
#pragma unroll
        for (int i = 0; i < 4; i++)
#pragma unroll
            for (int j = 0; j < 2; j++) acc[q][i][j] = z4;

    int bid = blockIdx.x;
    int wg  = (bid & 7) * 72 + (bid >> 3);     // 576 wgs, bijective (576%8==0)
    int m0  = (wg / 18) * 256;
    int n0  = (wg % 18) * 256;
    gemm256_core(ubf, wibf, DM, m0, n0, lds, acc);

    const int lane = threadIdx.x & 63, wave = threadIdx.x >> 6;
    const int wmq = wave >> 2, wnq = wave & 3;
#pragma unroll
    for (int q = 0; q < 4; q++) {
        const int mh = q >> 1, nh = (q & 1) ^ (q >> 1);
#pragma unroll
        for (int fm = 0; fm < 4; fm++) {
            const int gmb = m0 + mh * 128 + wmq * 64 + fm * 16 + ((lane >> 4) << 2);
#pragma unroll
            for (int fn = 0; fn < 2; fn++) {
                const int gn = n0 + nh * 128 + wnq * 32 + fn * 16 + (lane & 15);
                if (gn < DI) {
#pragma unroll
                    for (int r = 0; r < 4; r++)
                        zbuf[(size_t)(gmb + r) * DI + gn] = (__bf16)acc[q][fm][fn][r];
                } else if (gn < DI + CD) {
#pragma unroll
                    for (int r = 0; r < 4; r++)
                        xbcraw[(size_t)(gmb + r) * CD + (gn - DI)] = (__bf16)acc[q][fm][fn][r];
                } else if (gn < NOUT) {
                    const int hh = gn - (DI + CD);
                    const float bb = dt_bias[hh];
#pragma unroll
                    for (int r = 0; r < 4; r++) {
                        float x = acc[q][fm][fn][r] + bb;
                        float sp = (x > 20.f) ? x : log1pf(__expf(x));
                        dtbuf[(size_t)(gmb + r) * NH + hh] = sp;
                    }
                }
            }
        }
    }
}

// GEMM2: out = ynorm @ W_out^T  (256x128 tiles, grid 256 = 1/CU)
__global__ __launch_bounds__(512, 2) void k_gemm2(const __bf16* __restrict__ ybf, const __bf16* __restrict__ wobf,
                                                  float* __restrict__ out) {
    extern __shared__ char lds[];
    f32x4 acc[8][2];
    f32x4 z4 = {0.f, 0.f, 0.f, 0.f};
#pragma unroll
    for (int i = 0; i < 8; i++)
#pragma unroll
        for (int j = 0; j < 2; j++) acc[i][j] = z4;

    int bid = blockIdx.x;
    int wg  = (bid & 7) * 32 + (bid >> 3);     // 256 wgs
    int m0  = (wg / 8) * 256;
    int n0  = (wg % 8) * 128;
    gemm256x128_core(ybf, wobf, DI, m0, n0, lds, acc);

    const int lane = threadIdx.x & 63, wave = threadIdx.x >> 6;
    const int wmq = wave >> 2, wnq = wave & 3;
#pragma unroll
    for (int fm = 0; fm < 8; fm++) {
        const int gmb = m0 + wmq * 128 + fm * 16 + ((lane >> 4) << 2);
#pragma unroll
        for (int fn = 0; fn < 2; fn++) {
            const int gn = n0 + wnq * 32 + fn * 16 + (lane & 15);
#pragma unroll
            for (int r = 0; r < 4; r++)
                out[(size_t)(gmb + r) * DM + gn] = acc[fm][fn][r];
        }
    }
}

// ---------------- depthwise causal conv + SiLU ----------------
__global__ __launch_bounds__(256) void k_conv(const __bf16* __restrict__ xbcraw, const float* __restrict__ conv_w,
                                              const float* __restrict__ conv_b, __bf16* __restrict__ xconv) {
    size_t idx = (size_t)blockIdx.x * 256 + threadIdx.x;
    if (idx >= (size_t)ROWS * CD) return;
    int ch = (int)(idx % CD);
    size_t rem = idx / CD;
    int l = (int)(rem % L_);
    int b = (int)(rem / L_);
    float acc = conv_b[ch];
#pragma unroll
    for (int k = 0; k < 4; k++) {
        int ll = l - 3 + k;
        if (ll >= 0) acc += conv_w[ch * 4 + k] * (float)xbcraw[((size_t)b * L_ + ll) * CD + ch];
    }
    xconv[idx] = (__bf16)(acc / (1.f + __expf(-acc)));  // silu
}

// ---------------- CBT via MFMA: cbt[b][c][i][j] = sum_n C[i][n]*B[j][n] ----------------
__global__ __launch_bounds__(256) void k_cbt(const __bf16* __restrict__ xconv, float* __restrict__ cbt) {
    const int c = blockIdx.x, b = blockIdx.y;
    const int tid = threadIdx.x, wv = tid >> 6, lane = tid & 63;
    const int lrow = lane & 15, lko = (lane >> 4) * 8;
    __shared__ __align__(16) __bf16 Csh[64 * 136];
    __shared__ __align__(16) __bf16 Bsh[64 * 136];
    const size_t rowbase = (size_t)b * L_ + c * CHUNK;
#pragma unroll
    for (int q = 0; q < 32; q++) {
        int i = q * 2 + (wv >> 1);
        int n = (wv & 1) * 64 + lane;
        const __bf16* base = xconv + (rowbase + i) * CD + DI;
        Bsh[i * 136 + n] = base[n];
        Csh[i * 136 + n] = base[DS + n];
    }
    __syncthreads();
    f32x4 acc[4];
    f32x4 z4 = {0.f, 0.f, 0.f, 0.f};
#pragma unroll
    for (int jt = 0; jt < 4; jt++) acc[jt] = z4;
#pragma unroll
    for (int ks = 0; ks < 4; ks++) {
        bf16x8 a = *(const bf16x8*)&Csh[(wv * 16 + lrow) * 136 + ks * 32 + lko];
#pragma unroll
        for (int jt = 0; jt < 4; jt++) {
            bf16x8 bb = *(const bf16x8*)&Bsh[(jt * 16 + lrow) * 136 + ks * 32 + lko];
            acc[jt] = __builtin_amdgcn_mfma_f32_16x16x32_bf16(a, bb, acc[jt], 0, 0, 0);
        }
    }
    float* o = cbt + (size_t)(b * NC + c) * 4096;
#pragma unroll
    for (int jt = 0; jt < 4; jt++)
#pragma unroll
        for (int r = 0; r < 4; r++) {
            int i = wv * 16 + (lane >> 4) * 4 + r;
            int j = jt * 16 + lrow;
            o[i * 64 + j] = acc[jt][r];
        }
}

// ---------------- SSD part A (MFMA): Y_diag + D-skip, chunk states ----------------
__global__ __launch_bounds__(256) void k_ssd_a(const __bf16* __restrict__ xconv, const float* __restrict__ dtbuf,
                                               const float* __restrict__ cbt, const float* __restrict__ A_log,
                                               __bf16* __restrict__ ybuf, __bf16* __restrict__ states,
                                               float* __restrict__ asum, const float* __restrict__ D_param) {
    const int h = blockIdx.x, c = blockIdx.y, b = blockIdx.z;
    const int tid = threadIdx.x, wv = tid >> 6, lane = tid & 63;
    const int lrow = lane & 15, lko = (lane >> 4) * 8;
    __shared__ __align__(16) __bf16 xT[64 * 72];
    __shared__ __align__(16) __bf16 xsc[64 * 72];
    __shared__ __align__(16) __bf16 BT[128 * 72];
    __shared__ __align__(16) __bf16 Ms[64 * 72];
    __shared__ float dts[64], cum[64];

    const float Ah = -__expf(A_log[h]);
    const size_t rowbase = (size_t)b * L_ + c * CHUNK;

    float dtv = 0.f;
    if (wv == 0) { dtv = dtbuf[(rowbase + lane) * NH + h]; dts[lane] = dtv; }
#pragma unroll
    for (int q = 0; q < 16; q++) {
        int i = q * 4 + wv;
        xT[lane * 72 + i] = xconv[(rowbase + i) * CD + h * HD + lane];
    }
#pragma unroll
    for (int q = 0; q < 32; q++) {
        int i = q * 2 + (wv >> 1);
        int n = (wv & 1) * 64 + lane;
        BT[n * 72 + i] = xconv[(rowbase + i) * CD + DI + n];
    }
    if (wv == 0) {
        float v = Ah * dtv;
#pragma unroll
        for (int o = 1; o < 64; o <<= 1) { float t = __shfl_up(v, o); if (lane >= o) v += t; }
        cum[lane] = v;
        if (lane == 63) asum[(b * NC + c) * NH + h] = v;
    }
    __syncthreads();

    const float cum63 = cum[63];
    const float Dh = D_param[h];
    const float* cbt_bc = cbt + (size_t)(b * NC + c) * 4096;
#pragma unroll
    for (int q = 0; q < 16; q++) {
        int i = q * 4 + wv, j = lane;
        float cumi = cum[i];
        float m = 0.f;
        if (j <= i) m = cbt_bc[i * 64 + j] * __expf(cumi - cum[j]) * dts[j];
        if (j == i) m += Dh;
        Ms[i * 72 + j] = (__bf16)m;
        float dcfi = __expf(cum63 - cumi) * dts[i];
        xsc[lane * 72 + i] = (__bf16)((float)xT[lane * 72 + i] * dcfi);
    }
    __syncthreads();

    f32x4 z4 = {0.f, 0.f, 0.f, 0.f};
    {
        f32x4 accY[4];
#pragma unroll
        for (int pt = 0; pt < 4; pt++) accY[pt] = z4;
#pragma unroll
        for (int ks = 0; ks < 2; ks++) {
            bf16x8 a = *(const bf16x8*)&Ms[(wv * 16 + lrow) * 72 + ks * 32 + lko];
#pragma unroll
            for (int pt = 0; pt < 4; pt++) {
                bf16x8 bb = *(const bf16x8*)&xT[(pt * 16 + lrow) * 72 + ks * 32 + lko];
                accY[pt] = __builtin_amdgcn_mfma_f32_16x16x32_bf16(a, bb, accY[pt], 0, 0, 0);
            }
        }
#pragma unroll
        for (int pt = 0; pt < 4; pt++)
#pragma unroll
            for (int r = 0; r < 4; r++) {
                int i = wv * 16 + (lane >> 4) * 4 + r;
                int p = pt * 16 + lrow;
                ybuf[(rowbase + i) * DI + h * HD + p] = (__bf16)accY[pt][r];
            }
    }
    {
        f32x4 accS[8];
#pragma unroll
        for (int nt = 0; nt < 8; nt++) accS[nt] = z4;
#pragma unroll
        for (int ks = 0; ks < 2; ks++) {
            bf16x8 a = *(const bf16x8*)&xsc[(wv * 16 + lrow) * 72 + ks * 32 + lko];
#pragma unroll
            for (int nt = 0; nt < 8; nt++) {
                bf16x8 bb = *(const bf16x8*)&BT[(nt * 16 + lrow) * 72 + ks * 32 + lko];
                accS[nt] = __builtin_amdgcn_mfma_f32_16x16x32_bf16(a, bb, accS[nt], 0, 0, 0);
            }
        }
        __bf16* sp = states + ((size_t)(b * NC + c) * NH + h) * 8192;
#pragma unroll
        for (int nt = 0; nt < 8; nt++)
#pragma unroll
            for (int r = 0; r < 4; r++) {
                int p = wv * 16 + (lane >> 4) * 4 + r;
                int n = nt * 16 + lrow;
                sp[p * 128 + n] = (__bf16)accS[nt][r];
            }
    }
}

// ---------------- inter-chunk scan (in-place: chunk_states -> states_prev) ----------------
__global__ __launch_bounds__(256) void k_scan(__bf16* __restrict__ states, const float* __restrict__ asum) {
    const int seg = blockIdx.x, h = blockIdx.y, b = blockIdx.z;
    const int e0 = seg * 1024 + threadIdx.x * 4;
    float S[4] = {0.f, 0.f, 0.f, 0.f};
    for (int c = 0; c < NC; c++) {
        float ef = __expf(asum[(b * NC + c) * NH + h]);
        __bf16* ptr = states + (((size_t)(b * NC + c) * NH + h) * 8192) + e0;
        s16x4 raw = *(const s16x4*)ptr;
        s16x4 outv;
#pragma unroll
        for (int q = 0; q < 4; q++) {
            float t = (float)__builtin_bit_cast(__bf16, (short)raw[q]);
            outv[q] = __builtin_bit_cast(short, (__bf16)S[q]);
            S[q] = ef * S[q] + t;
        }
        *(s16x4*)ptr = outv;
    }
}

// ---------------- SSD part B (MFMA): Y += exp(cum[i]) * C @ Sprev^T ----------------
__global__ __launch_bounds__(256) void k_ssd_b(const __bf16* __restrict__ xconv, const float* __restrict__ dtbuf,
                                               const __bf16* __restrict__ states, const float* __restrict__ A_log,
                                               __bf16* __restrict__ ybuf) {
    const int h = blockIdx.x, c = blockIdx.y, b = blockIdx.z;
    const int tid = threadIdx.x, wv = tid >> 6, lane = tid & 63;
    const int lrow = lane & 15, lko = (lane >> 4) * 8;
    __shared__ __align__(16) __bf16 Csh[64 * 136];
    __shared__ __align__(16) __bf16 Sps[64 * 136];
    __shared__ float cum[64];

    const float Ah = -__expf(A_log[h]);
    const size_t rowbase = (size_t)b * L_ + c * CHUNK;
    const __bf16* sp = states + ((size_t)(b * NC + c) * NH + h) * 8192;
#pragma unroll
    for (int q = 0; q < 32; q++) {
        int i = q * 2 + (wv >> 1);
        int n = (wv & 1) * 64 + lane;
        Csh[i * 136 + n] = xconv[(rowbase + i) * CD + DI + DS + n];
        Sps[i * 136 + n] = sp[i * 128 + n];
    }
    if (wv == 0) {
        float v = Ah * dtbuf[(rowbase + lane) * NH + h];
#pragma unroll
        for (int o = 1; o < 64; o <<= 1) { float t = __shfl_up(v, o); if (lane >= o) v += t; }
        cum[lane] = v;
    }
    __syncthreads();

    f32x4 acc[4];
    f32x4 z4 = {0.f, 0.f, 0.f, 0.f};
#pragma unroll
    for (int pt = 0; pt < 4; pt++) acc[pt] = z4;
#pragma unroll
    for (int ks = 0; ks < 4; ks++) {
        bf16x8 a = *(const bf16x8*)&Csh[(wv * 16 + lrow) * 136 + ks * 32 + lko];
#pragma unroll
        for (int pt = 0; pt < 4; pt++) {
            bf16x8 bb = *(const bf16x8*)&Sps[(pt * 16 + lrow) * 136 + ks * 32 + lko];
            acc[pt] = __builtin_amdgcn_mfma_f32_16x16x32_bf16(a, bb, acc[pt], 0, 0, 0);
        }
    }
#pragma unroll
    for (int r = 0; r < 4; r++) {
        int i = wv * 16 + (lane >> 4) * 4 + r;
        float ef = __expf(cum[i]);
#pragma unroll
        for (int pt = 0; pt < 4; pt++) {
            size_t idx = (rowbase + i) * DI + h * HD + pt * 16 + lrow;
            float y0 = (float)ybuf[idx];
            ybuf[idx] = (__bf16)(y0 + ef * acc[pt][r]);
        }
    }
}

// ---------------- gate (silu(z)) + RMSNorm -> bf16 ----------------
__global__ __launch_bounds__(256) void k_gate_norm(const __bf16* __restrict__ ybuf, const __bf16* __restrict__ zbuf,
                                                   const float* __restrict__ norm_w, __bf16* __restrict__ ybf) {
    const int r = blockIdx.x;
    const int tid = threadIdx.x;
    float v[8];
    float ss = 0.f;
#pragma unroll
    for (int q = 0; q < 8; q++) {
        int col = q * 256 + tid;
        float y = (float)ybuf[(size_t)r * DI + col];
        float z = (float)zbuf[(size_t)r * DI + col];
        float g = z / (1.f + __expf(-z));
        float val = y * g;
        v[q] = val;
        ss += val * val;
    }
#pragma unroll
    for (int o = 32; o > 0; o >>= 1) ss += __shfl_down(ss, o);
    __shared__ float wsum[4];
    __shared__ float rmss;
    if ((tid & 63) == 0) wsum[tid >> 6] = ss;
    __syncthreads();
    if (tid == 0) {
        float t = wsum[0] + wsum[1] + wsum[2] + wsum[3];
        rmss = rsqrtf(t / (float)DI + 1e-5f);
    }
    __syncthreads();
    float rm = rmss;
#pragma unroll
    for (int q = 0; q < 8; q++) {
        int col = q * 256 + tid;
        ybf[(size_t)r * DI + col] = (__bf16)(v[q] * rm * norm_w[col]);
    }
}

// ---------------- launcher ----------------
extern "C" void kernel_launch(void* const* d_in, const int* in_sizes, int n_in,
                              void* d_out, int out_size, void* d_ws, size_t ws_size,
                              hipStream_t stream) {
    const float* u       = (const float*)d_in[0];
    const float* W_in    = (const float*)d_in[1];
    const float* conv_w  = (const float*)d_in[2];
    const float* conv_b  = (const float*)d_in[3];
    const float* dt_bias = (const float*)d_in[4];
    const float* A_log   = (const float*)d_in[5];
    const float* D_param = (const float*)d_in[6];
    const float* norm_w  = (const float*)d_in[7];
    const float* W_out   = (const float*)d_in[8];
    float* out = (float*)d_out;

    // ---- static workspace plan (145.8 MB total) ----
    constexpr size_t OFF_WOBF  = 0;
    constexpr size_t OFF_ZBUF  = 4194304;
    constexpr size_t OFF_DT    = 37748736;
    constexpr size_t OFF_ASUM  = 38797312;
    constexpr size_t OFF_XCONV = 38813696;
    constexpr size_t OFF_CBT   = 76562432;
    constexpr size_t OFF_BIG   = 78659584;
    constexpr size_t NEED      = 145768448;
    if (ws_size < NEED) return;

    char* ws = (char*)d_ws;
    __bf16* wobf   = (__bf16*)(ws + OFF_WOBF);
    __bf16* zbuf   = (__bf16*)(ws + OFF_ZBUF);
    float*  dtbuf  = (float*) (ws + OFF_DT);
    float*  asum   = (float*) (ws + OFF_ASUM);
    __bf16* xconv  = (__bf16*)(ws + OFF_XCONV);
    float*  cbt    = (float*) (ws + OFF_CBT);
    __bf16* ubf    = (__bf16*)(ws + OFF_BIG);
    __bf16* wibf   = (__bf16*)(ws + OFF_BIG + 16777216);
    __bf16* xbcraw = (__bf16*)(ws + OFF_BIG + 16777216 + 9437184);
    __bf16* states = (__bf16*)(ws + OFF_BIG);          // reuses ubf/wibf/xbcraw after conv
    __bf16* ybf    = (__bf16*)(ws + OFF_XCONV);        // reuses xconv after ssd_b
    __bf16* ybuf   = (__bf16*)d_out;                   // bf16 scratch, overwritten by gemm2

    (void)hipFuncSetAttribute((const void*)k_gemm1, hipFuncAttributeMaxDynamicSharedMemorySize, 131072);
    (void)hipFuncSetAttribute((const void*)k_gemm2, hipFuncAttributeMaxDynamicSharedMemorySize, 147456);

    k_f32_to_bf16<<<(ROWS * DM + 255) / 256, 256, 0, stream>>>(u, ubf, ROWS * DM);
    k_convert_pad<<<(NPAD2 * DM + 255) / 256, 256, 0, stream>>>(W_in, wibf, NOUT * DM, NPAD2 * DM);
    k_f32_to_bf16<<<(DM * DI + 255) / 256, 256, 0, stream>>>(W_out, wobf, DM * DI);

    k_gemm1<<<576, 512, 131072, stream>>>(ubf, wibf, zbuf, xbcraw, dtbuf, dt_bias);
    k_conv<<<(int)(((size_t)ROWS * CD + 255) / 256), 256, 0, stream>>>(xbcraw, conv_w, conv_b, xconv);
    k_cbt<<<dim3(NC, B_), 256, 0, stream>>>(xconv, cbt);
    k_ssd_a<<<dim3(NH, NC, B_), 256, 0, stream>>>(xconv, dtbuf, cbt, A_log, ybuf, states, asum, D_param);
    k_scan<<<dim3(8, NH, B_), 256, 0, stream>>>(states, asum);
    k_ssd_b<<<dim3(NH, NC, B_), 256, 0, stream>>>(xconv, dtbuf, states, A_log, ybuf);
    k_gate_norm<<<ROWS, 256, 0, stream>>>(ybuf, zbuf, norm_w, ybf);
    k_gemm2<<<256, 512, 147456, stream>>>(ybf, wobf, out);
}